// Round 1
// baseline (700.176 us; speedup 1.0000x reference)
//
#include <hip/hip_runtime.h>

#define NEG_SLOPE 0.1f

// ---------------- CSR build ----------------

__global__ void k_count(const int* __restrict__ ei, int E, int* __restrict__ deg) {
    int e = blockIdx.x * 256 + threadIdx.x;
    if (e < E) atomicAdd(&deg[ei[E + e]], 1);
}

// Per-wave exclusive prefix of degrees; segment base via one atomic per wave.
// Segment order across waves is nondeterministic but irrelevant (summation).
__global__ void k_starts(const int* __restrict__ deg, int N, int* __restrict__ start,
                         int* __restrict__ cursor, int* __restrict__ counter) {
    int n = blockIdx.x * 256 + threadIdx.x;
    int lane = threadIdx.x & 63;
    int d = (n < N) ? deg[n] : 0;
    int inc = d;
#pragma unroll
    for (int o = 1; o < 64; o <<= 1) {
        int v = __shfl_up(inc, o);
        if (lane >= o) inc += v;
    }
    int total = __shfl(inc, 63);
    int base = 0;
    if (lane == 0) base = atomicAdd(counter, total);
    base = __shfl(base, 0);
    int st = base + inc - d;
    if (n < N) { start[n] = st; cursor[n] = st; }
}

__global__ void k_fill(const int* __restrict__ ei, int E, int* __restrict__ cursor,
                       int* __restrict__ adj) {
    int e = blockIdx.x * 256 + threadIdx.x;
    if (e < E) {
        int s = ei[e];
        int dv = ei[E + e];
        int p = atomicAdd(&cursor[dv], 1);
        adj[p] = s;
    }
}

// ---------------- mean aggregation: one wave per dst node ----------------

__global__ __launch_bounds__(256) void k_agg(const float* __restrict__ x,
                                             const int* __restrict__ adj,
                                             const int* __restrict__ start,
                                             const int* __restrict__ deg,
                                             float* __restrict__ agg, int N) {
    int w = (blockIdx.x * 256 + threadIdx.x) >> 6;  // node index
    int lane = threadIdx.x & 63;
    if (w >= N) return;
    int st = start[w], cnt = deg[w];
    float ax = 0.f, ay = 0.f;
    for (int i = 0; i < cnt; i++) {
        int s = adj[st + i];
        const float2 v = *reinterpret_cast<const float2*>(x + ((size_t)s << 7) + (lane << 1));
        ax += v.x;
        ay += v.y;
    }
    float inv = 1.0f / fmaxf((float)cnt, 1.0f);
    float2 o;
    o.x = ax * inv;
    o.y = ay * inv;
    *reinterpret_cast<float2*>(agg + ((size_t)w << 7) + (lane << 1)) = o;
}

// ---------------- fused f32 GEMM: out = act(A1@W1 [+ A2@W2] + bias) ----------------
// K fixed at 128. BM=64, BK=32. 256 threads: 16 thread-rows x 16 thread-cols,
// micro-tile 4 rows x (BN/16) cols per thread.

template <int BN, bool SECOND, bool ACT>
__global__ __launch_bounds__(256) void k_gemm(const float* __restrict__ A1,
                                              const float* __restrict__ W1,
                                              const float* __restrict__ A2,
                                              const float* __restrict__ W2,
                                              const float* __restrict__ bias,
                                              float* __restrict__ out, int M) {
    constexpr int BM = 64, BK = 32, K = 128;
    constexpr int NC = BN / 16;   // cols per thread: 8 (BN=128) or 4 (BN=64)
    constexpr int APAD = 36;      // padded row stride (floats) for A tiles

    __shared__ float A1s[BM * APAD];
    __shared__ float W1s[BK * BN];
    __shared__ float A2s[SECOND ? BM * APAD : 4];
    __shared__ float W2s[SECOND ? BK * BN : 4];

    const int tid = threadIdx.x;
    const int m0 = blockIdx.x * BM;
    const int tr = tid >> 4, tc = tid & 15;
    const int r0 = tr * 4, c0 = tc * NC;

    float acc[4][NC];
#pragma unroll
    for (int i = 0; i < 4; i++)
#pragma unroll
        for (int j = 0; j < NC; j++) acc[i][j] = 0.f;

    for (int kt = 0; kt < K; kt += BK) {
        __syncthreads();
        // stage A tiles: 64x32 floats = 512 float4, 2 per thread
#pragma unroll
        for (int q = 0; q < 2; q++) {
            int idx = tid * 2 + q;       // 0..511
            int r = idx >> 3, kq = idx & 7;
            int row = m0 + r;
            if (row >= M) row = M - 1;   // clamp; stores are guarded later
            float4 v = *reinterpret_cast<const float4*>(A1 + (size_t)row * K + kt + kq * 4);
            *reinterpret_cast<float4*>(&A1s[r * APAD + kq * 4]) = v;
            if constexpr (SECOND) {
                float4 u = *reinterpret_cast<const float4*>(A2 + (size_t)row * K + kt + kq * 4);
                *reinterpret_cast<float4*>(&A2s[r * APAD + kq * 4]) = u;
            }
        }
        // stage W tiles: BK x BN floats
        constexpr int WQ = (BK * BN / 4) / 256;  // 4 (BN=128) or 2 (BN=64)
#pragma unroll
        for (int q = 0; q < WQ; q++) {
            int idx = tid + q * 256;       // float4 index
            int kk = idx / (BN / 4), cq = idx % (BN / 4);
            float4 v = *reinterpret_cast<const float4*>(W1 + (size_t)(kt + kk) * BN + cq * 4);
            *reinterpret_cast<float4*>(&W1s[kk * BN + cq * 4]) = v;
            if constexpr (SECOND) {
                float4 u = *reinterpret_cast<const float4*>(W2 + (size_t)(kt + kk) * BN + cq * 4);
                *reinterpret_cast<float4*>(&W2s[kk * BN + cq * 4]) = u;
            }
        }
        __syncthreads();

#pragma unroll 8
        for (int kk = 0; kk < BK; kk++) {
            float a1[4], a2[4];
#pragma unroll
            for (int i = 0; i < 4; i++) {
                a1[i] = A1s[(r0 + i) * APAD + kk];
                if constexpr (SECOND) a2[i] = A2s[(r0 + i) * APAD + kk];
            }
            float w1[NC], w2[NC];
#pragma unroll
            for (int j = 0; j < NC; j += 4) {
                float4 v = *reinterpret_cast<const float4*>(&W1s[kk * BN + c0 + j]);
                w1[j] = v.x; w1[j + 1] = v.y; w1[j + 2] = v.z; w1[j + 3] = v.w;
                if constexpr (SECOND) {
                    float4 u = *reinterpret_cast<const float4*>(&W2s[kk * BN + c0 + j]);
                    w2[j] = u.x; w2[j + 1] = u.y; w2[j + 2] = u.z; w2[j + 3] = u.w;
                }
            }
#pragma unroll
            for (int i = 0; i < 4; i++)
#pragma unroll
                for (int j = 0; j < NC; j++) {
                    acc[i][j] = fmaf(a1[i], w1[j], acc[i][j]);
                    if constexpr (SECOND) acc[i][j] = fmaf(a2[i], w2[j], acc[i][j]);
                }
        }
    }

    // epilogue
    float bv[NC];
#pragma unroll
    for (int j = 0; j < NC; j++) bv[j] = bias[c0 + j];

#pragma unroll
    for (int i = 0; i < 4; i++) {
        int row = m0 + r0 + i;
        if (row < M) {
#pragma unroll
            for (int j = 0; j < NC; j += 4) {
                float4 o;
                float* oo = reinterpret_cast<float*>(&o);
#pragma unroll
                for (int jj = 0; jj < 4; jj++) {
                    float v = acc[i][j + jj] + bv[j + jj];
                    if (ACT) v = v > 0.f ? v : NEG_SLOPE * v;
                    oo[jj] = v;
                }
                *reinterpret_cast<float4*>(out + (size_t)row * BN + c0 + j) = o;
            }
        }
    }
}

// ---------------- launch ----------------

extern "C" void kernel_launch(void* const* d_in, const int* in_sizes, int n_in,
                              void* d_out, int out_size, void* d_ws, size_t ws_size,
                              hipStream_t stream) {
    const float* x    = (const float*)d_in[0];
    const int*   ei   = (const int*)d_in[1];
    const float* wl   = (const float*)d_in[2];
    const float* wr   = (const float*)d_in[3];
    const float* bc   = (const float*)d_in[4];
    const float* wlin = (const float*)d_in[5];
    const float* blin = (const float*)d_in[6];
    const float* wout = (const float*)d_in[7];
    const float* bout = (const float*)d_in[8];
    float* out = (float*)d_out;

    const int N = in_sizes[0] / 128;
    const int E = in_sizes[1] / 2;

    char* p = (char*)d_ws;
    auto alloc = [&](size_t bytes) {
        char* r = p;
        p += (bytes + 255) & ~(size_t)255;
        return r;
    };
    int* counter = (int*)alloc(4);
    int* deg     = (int*)alloc((size_t)N * 4);
    int* start   = (int*)alloc((size_t)N * 4);
    int* cursor  = (int*)alloc((size_t)N * 4);
    int* adj     = (int*)alloc((size_t)E * 4);
    float* agg   = (float*)alloc((size_t)N * 128 * 4);
    float* hA    = (float*)alloc((size_t)N * 128 * 4);
    float* hB    = (float*)alloc((size_t)N * 128 * 4);

    // zero counter + deg (contiguous at the front of ws)
    hipMemsetAsync(d_ws, 0, (size_t)((char*)(deg + N) - (char*)d_ws), stream);

    const int gE = (E + 255) / 256;
    const int gN = (N + 255) / 256;
    const int gW = (N * 64 + 255) / 256;  // one wave per node
    const int gM = (N + 63) / 64;

    k_count <<<gE, 256, 0, stream>>>(ei, E, deg);
    k_starts<<<gN, 256, 0, stream>>>(deg, N, start, cursor, counter);
    k_fill  <<<gE, 256, 0, stream>>>(ei, E, cursor, adj);

    // layer 0
    k_agg<<<gW, 256, 0, stream>>>(x, adj, start, deg, agg, N);
    k_gemm<128, true,  true ><<<gM, 256, 0, stream>>>(agg, wl,              x,  wr,              bc,       hA, N);
    k_gemm<128, false, true ><<<gM, 256, 0, stream>>>(hA,  wlin,            nullptr, nullptr,    blin,     hB, N);
    // layer 1
    k_agg<<<gW, 256, 0, stream>>>(hB, adj, start, deg, agg, N);
    k_gemm<128, true,  true ><<<gM, 256, 0, stream>>>(agg, wl + 16384,      hB, wr + 16384,      bc + 128, hA, N);
    k_gemm<128, false, true ><<<gM, 256, 0, stream>>>(hA,  wlin + 16384,    nullptr, nullptr,    blin + 128, hB, N);
    // layer 2 (no activation)
    k_agg<<<gW, 256, 0, stream>>>(hB, adj, start, deg, agg, N);
    k_gemm<128, true,  false><<<gM, 256, 0, stream>>>(agg, wl + 32768,      hB, wr + 32768,      bc + 256, hA, N);
    // output projection
    k_gemm<64,  false, false><<<gM, 256, 0, stream>>>(hA,  wout,            nullptr, nullptr,    bout,     out, N);
}

// Round 2
// 505.339 us; speedup vs baseline: 1.3856x; 1.3856x over previous
//
#include <hip/hip_runtime.h>

#define NEG_SLOPE 0.1f

typedef __bf16 bf16x8 __attribute__((ext_vector_type(8)));
typedef float f32x4 __attribute__((ext_vector_type(4)));
typedef unsigned int uint32x4 __attribute__((ext_vector_type(4)));
typedef unsigned int uint32x2 __attribute__((ext_vector_type(2)));
typedef unsigned short ushort;

__device__ inline ushort f2bf(float f) {
    unsigned int u = __float_as_uint(f);
    u += 0x7fffu + ((u >> 16) & 1u);
    return (ushort)(u >> 16);
}
__device__ inline float bf2f(ushort h) { return __uint_as_float(((unsigned int)h) << 16); }

// ---------------- CSR build ----------------

__global__ void k_count(const int* __restrict__ ei, int E, int* __restrict__ deg) {
    int e = blockIdx.x * 256 + threadIdx.x;
    if (e < E) atomicAdd(&deg[ei[E + e]], 1);
}

__global__ void k_starts(const int* __restrict__ deg, int N, int* __restrict__ start,
                         int* __restrict__ cursor, int* __restrict__ counter) {
    int n = blockIdx.x * 256 + threadIdx.x;
    int lane = threadIdx.x & 63;
    int d = (n < N) ? deg[n] : 0;
    int inc = d;
#pragma unroll
    for (int o = 1; o < 64; o <<= 1) {
        int v = __shfl_up(inc, o);
        if (lane >= o) inc += v;
    }
    int total = __shfl(inc, 63);
    int base = 0;
    if (lane == 0) base = atomicAdd(counter, total);
    base = __shfl(base, 0);
    int st = base + inc - d;
    if (n < N) { start[n] = st; cursor[n] = st; }
}

__global__ void k_fill(const int* __restrict__ ei, int E, int* __restrict__ cursor,
                       int* __restrict__ adj) {
    int e = blockIdx.x * 256 + threadIdx.x;
    if (e < E) {
        int s = ei[e];
        int dv = ei[E + e];
        int p = atomicAdd(&cursor[dv], 1);
        adj[p] = s;
    }
}

// ---------------- weight pre-pack: W[K][Nn] f32 -> packed hi/lo bf16 ----------------
// packed layout: [Nn/16 cb][16 kg][16 col][8 k]  (chunk = 16B of 8 contiguous k)

__global__ __launch_bounds__(256) void k_wpack(const float* __restrict__ wl,
                                               const float* __restrict__ wr,
                                               const float* __restrict__ wlin,
                                               const float* __restrict__ wout,
                                               ushort* __restrict__ wph,
                                               ushort* __restrict__ wpl) {
    int m = blockIdx.y;
    int c = blockIdx.x * 256 + threadIdx.x;
    const float* src;
    int Nn = 128;
    size_t dstoff;
    if (m < 3)      { src = wl   + (size_t)m * 16384;       dstoff = (size_t)m * 16384; }
    else if (m < 6) { src = wr   + (size_t)(m - 3) * 16384; dstoff = (size_t)m * 16384; }
    else if (m < 8) { src = wlin + (size_t)(m - 6) * 16384; dstoff = (size_t)m * 16384; }
    else            { src = wout; Nn = 64;                  dstoff = (size_t)8 * 16384; }
    if (c >= Nn * 16) return;
    int cb = c >> 8, gg = (c >> 4) & 15, col = c & 15;
    ushort hi[8], lo[8];
#pragma unroll
    for (int j = 0; j < 8; j++) {
        float v = src[(size_t)(gg * 8 + j) * Nn + cb * 16 + col];
        ushort h = f2bf(v);
        hi[j] = h;
        lo[j] = f2bf(v - bf2f(h));
    }
    uint32x4 hv, lv;
    hv.x = hi[0] | ((unsigned)hi[1] << 16); hv.y = hi[2] | ((unsigned)hi[3] << 16);
    hv.z = hi[4] | ((unsigned)hi[5] << 16); hv.w = hi[6] | ((unsigned)hi[7] << 16);
    lv.x = lo[0] | ((unsigned)lo[1] << 16); lv.y = lo[2] | ((unsigned)lo[3] << 16);
    lv.z = lo[4] | ((unsigned)lo[5] << 16); lv.w = lo[6] | ((unsigned)lo[7] << 16);
    *(uint32x4*)(wph + dstoff + (size_t)c * 8) = hv;
    *(uint32x4*)(wpl + dstoff + (size_t)c * 8) = lv;
}

// ---------------- x f32 -> packed hi/lo ----------------

__global__ __launch_bounds__(256) void k_splitx(const float* __restrict__ x,
                                                ushort* __restrict__ oh,
                                                ushort* __restrict__ ol, int N) {
    int t = blockIdx.x * 256 + threadIdx.x;
    int row = t >> 4, g = t & 15;
    if (row >= N) return;
    const float* src = x + (size_t)row * 128 + g * 8;
    ushort hi[8], lo[8];
#pragma unroll
    for (int j = 0; j < 8; j++) {
        float v = src[j];
        ushort h = f2bf(v);
        hi[j] = h;
        lo[j] = f2bf(v - bf2f(h));
    }
    uint32x4 hv, lv;
    hv.x = hi[0] | ((unsigned)hi[1] << 16); hv.y = hi[2] | ((unsigned)hi[3] << 16);
    hv.z = hi[4] | ((unsigned)hi[5] << 16); hv.w = hi[6] | ((unsigned)hi[7] << 16);
    lv.x = lo[0] | ((unsigned)lo[1] << 16); lv.y = lo[2] | ((unsigned)lo[3] << 16);
    lv.z = lo[4] | ((unsigned)lo[5] << 16); lv.w = lo[6] | ((unsigned)lo[7] << 16);
    size_t off = ((size_t)(row >> 4) * 16 + g) * 128 + (row & 15) * 8;
    *(uint32x4*)(oh + off) = hv;
    *(uint32x4*)(ol + off) = lv;
}

// ---------------- mean aggregation: wave per node, 2 edges/iter, packed hi/lo out ----

__global__ __launch_bounds__(256) void k_agg(const float* __restrict__ xf,
                                             const int* __restrict__ adj,
                                             const int* __restrict__ start,
                                             const int* __restrict__ deg,
                                             ushort* __restrict__ oh,
                                             ushort* __restrict__ ol, int N) {
    int w = (blockIdx.x * 256 + threadIdx.x) >> 6;
    if (w >= N) return;
    int lane = threadIdx.x & 63;
    int h = lane >> 5, q = lane & 31;
    int st = start[w], cnt = deg[w];
    float ax = 0.f, ay = 0.f, az = 0.f, aw = 0.f;
    int i = 0;
    for (; i + 4 <= cnt; i += 4) {
        int s0 = adj[st + i + h];
        int s1 = adj[st + i + 2 + h];
        float4 v0 = *(const float4*)(xf + ((size_t)s0 << 7) + (q << 2));
        float4 v1 = *(const float4*)(xf + ((size_t)s1 << 7) + (q << 2));
        ax += v0.x + v1.x; ay += v0.y + v1.y; az += v0.z + v1.z; aw += v0.w + v1.w;
    }
    for (; i + 2 <= cnt; i += 2) {
        int s0 = adj[st + i + h];
        float4 v0 = *(const float4*)(xf + ((size_t)s0 << 7) + (q << 2));
        ax += v0.x; ay += v0.y; az += v0.z; aw += v0.w;
    }
    if (i + h < cnt) {
        int s0 = adj[st + i + h];
        float4 v0 = *(const float4*)(xf + ((size_t)s0 << 7) + (q << 2));
        ax += v0.x; ay += v0.y; az += v0.z; aw += v0.w;
    }
    ax += __shfl_xor(ax, 32); ay += __shfl_xor(ay, 32);
    az += __shfl_xor(az, 32); aw += __shfl_xor(aw, 32);
    float inv = 1.0f / fmaxf((float)cnt, 1.0f);
    float v[4] = {ax * inv, ay * inv, az * inv, aw * inv};
    ushort hi[4], lo[4];
#pragma unroll
    for (int c = 0; c < 4; c++) {
        ushort hh = f2bf(v[c]);
        hi[c] = hh;
        lo[c] = f2bf(v[c] - bf2f(hh));
    }
    const ushort* src = h ? lo : hi;
    uint32x2 val;
    val.x = src[0] | ((unsigned)src[1] << 16);
    val.y = src[2] | ((unsigned)src[3] << 16);
    size_t off = (((size_t)(w >> 4) * 16 + (q >> 1)) * 16 + (w & 15)) * 8 + (q & 1) * 4;
    *(uint32x2*)((h ? ol : oh) + off) = val;
}

// ---------------- split-bf16 MFMA GEMM ----------------
// out[M x NMAT] = act(A1@W1 [+ A2@W2] + bias); A,W packed hi/lo bf16.
// Block: 4 waves x 64 rows, 32 cols; grid = (ceil(M/256), NMAT/32).

template <int NMAT, bool SECOND, bool ACT, bool WPACK, bool WF32>
__global__ __launch_bounds__(256) void k_gemm(
    const ushort* __restrict__ A1h, const ushort* __restrict__ A1l,
    const ushort* __restrict__ A2h, const ushort* __restrict__ A2l,
    const ushort* __restrict__ W1h, const ushort* __restrict__ W1l,
    const ushort* __restrict__ W2h, const ushort* __restrict__ W2l,
    const float* __restrict__ bias,
    ushort* __restrict__ Oph, ushort* __restrict__ Opl,
    float* __restrict__ Of32, int M) {
    __shared__ float tile[4][64][33];
    const int tid = threadIdx.x;
    const int w = tid >> 6, lane = tid & 63;
    const int g = lane >> 4, r16 = lane & 15;
    const int Mrb = M >> 4;
    const int rb0 = blockIdx.x * 16 + w * 4;
    const int laneA = g * 128 + r16 * 8;

    f32x4 acc[4][2] = {};

#pragma unroll
    for (int s = 0; s < 4; s++) {
        bf16x8 a1h[4], a1l[4], a2h[4], a2l[4];
#pragma unroll
        for (int rf = 0; rf < 4; rf++) {
            int rb = rb0 + rf;
            if (rb > Mrb - 1) rb = Mrb - 1;
            size_t off = (size_t)rb * 2048 + s * 512 + laneA;
            a1h[rf] = *(const bf16x8*)(A1h + off);
            a1l[rf] = *(const bf16x8*)(A1l + off);
            if constexpr (SECOND) {
                a2h[rf] = *(const bf16x8*)(A2h + off);
                a2l[rf] = *(const bf16x8*)(A2l + off);
            }
        }
        bf16x8 b1h[2], b1l[2], b2h[2], b2l[2];
#pragma unroll
        for (int cf = 0; cf < 2; cf++) {
            size_t off = (size_t)(blockIdx.y * 2 + cf) * 2048 + s * 512 + laneA;
            b1h[cf] = *(const bf16x8*)(W1h + off);
            b1l[cf] = *(const bf16x8*)(W1l + off);
            if constexpr (SECOND) {
                b2h[cf] = *(const bf16x8*)(W2h + off);
                b2l[cf] = *(const bf16x8*)(W2l + off);
            }
        }
#pragma unroll
        for (int rf = 0; rf < 4; rf++)
#pragma unroll
            for (int cf = 0; cf < 2; cf++)
                acc[rf][cf] = __builtin_amdgcn_mfma_f32_16x16x32_bf16(a1h[rf], b1h[cf], acc[rf][cf], 0, 0, 0);
#pragma unroll
        for (int rf = 0; rf < 4; rf++)
#pragma unroll
            for (int cf = 0; cf < 2; cf++)
                acc[rf][cf] = __builtin_amdgcn_mfma_f32_16x16x32_bf16(a1h[rf], b1l[cf], acc[rf][cf], 0, 0, 0);
#pragma unroll
        for (int rf = 0; rf < 4; rf++)
#pragma unroll
            for (int cf = 0; cf < 2; cf++)
                acc[rf][cf] = __builtin_amdgcn_mfma_f32_16x16x32_bf16(a1l[rf], b1h[cf], acc[rf][cf], 0, 0, 0);
        if constexpr (SECOND) {
#pragma unroll
            for (int rf = 0; rf < 4; rf++)
#pragma unroll
                for (int cf = 0; cf < 2; cf++)
                    acc[rf][cf] = __builtin_amdgcn_mfma_f32_16x16x32_bf16(a2h[rf], b2h[cf], acc[rf][cf], 0, 0, 0);
#pragma unroll
            for (int rf = 0; rf < 4; rf++)
#pragma unroll
                for (int cf = 0; cf < 2; cf++)
                    acc[rf][cf] = __builtin_amdgcn_mfma_f32_16x16x32_bf16(a2h[rf], b2l[cf], acc[rf][cf], 0, 0, 0);
#pragma unroll
            for (int rf = 0; rf < 4; rf++)
#pragma unroll
                for (int cf = 0; cf < 2; cf++)
                    acc[rf][cf] = __builtin_amdgcn_mfma_f32_16x16x32_bf16(a2l[rf], b2h[cf], acc[rf][cf], 0, 0, 0);
        }
    }

    float bv[2];
#pragma unroll
    for (int cf = 0; cf < 2; cf++) bv[cf] = bias[(blockIdx.y * 2 + cf) * 16 + r16];

    const int row_base = blockIdx.x * 256 + w * 64;
#pragma unroll
    for (int rf = 0; rf < 4; rf++)
#pragma unroll
        for (int cf = 0; cf < 2; cf++)
#pragma unroll
            for (int i = 0; i < 4; i++) {
                float v = acc[rf][cf][i] + bv[cf];
                if (ACT) v = v > 0.f ? v : NEG_SLOPE * v;
                tile[w][rf * 16 + g * 4 + i][cf * 16 + r16] = v;
                if constexpr (WF32) {
                    int row = row_base + rf * 16 + g * 4 + i;
                    if (row < M)
                        Of32[(size_t)row * NMAT + blockIdx.y * 32 + cf * 16 + r16] = v;
                }
            }

    if constexpr (WPACK) {
        __syncthreads();
#pragma unroll
        for (int rep = 0; rep < 4; rep++) {
            int id = rep * 64 + lane;
            int rl = id >> 2, gl = id & 3;
            int row = row_base + rl;
            if (row < M) {
                ushort hi[8], lo[8];
#pragma unroll
                for (int k = 0; k < 8; k++) {
                    float v = tile[w][rl][gl * 8 + k];
                    ushort hh = f2bf(v);
                    hi[k] = hh;
                    lo[k] = f2bf(v - bf2f(hh));
                }
                uint32x4 hv, lv;
                hv.x = hi[0] | ((unsigned)hi[1] << 16); hv.y = hi[2] | ((unsigned)hi[3] << 16);
                hv.z = hi[4] | ((unsigned)hi[5] << 16); hv.w = hi[6] | ((unsigned)hi[7] << 16);
                lv.x = lo[0] | ((unsigned)lo[1] << 16); lv.y = lo[2] | ((unsigned)lo[3] << 16);
                lv.z = lo[4] | ((unsigned)lo[5] << 16); lv.w = lo[6] | ((unsigned)lo[7] << 16);
                size_t off = ((size_t)(row >> 4) * 16 + (blockIdx.y * 4 + gl)) * 128 + (row & 15) * 8;
                *(uint32x4*)(Oph + off) = hv;
                *(uint32x4*)(Opl + off) = lv;
            }
        }
    }
}

// ---------------- launch ----------------

extern "C" void kernel_launch(void* const* d_in, const int* in_sizes, int n_in,
                              void* d_out, int out_size, void* d_ws, size_t ws_size,
                              hipStream_t stream) {
    const float* x    = (const float*)d_in[0];
    const int*   ei   = (const int*)d_in[1];
    const float* wl   = (const float*)d_in[2];
    const float* wr   = (const float*)d_in[3];
    const float* bc   = (const float*)d_in[4];
    const float* wlin = (const float*)d_in[5];
    const float* blin = (const float*)d_in[6];
    const float* wout = (const float*)d_in[7];
    const float* bout = (const float*)d_in[8];
    float* out = (float*)d_out;

    const int N = in_sizes[0] / 128;
    const int E = in_sizes[1] / 2;

    char* p = (char*)d_ws;
    auto alloc = [&](size_t bytes) {
        char* r = p;
        p += (bytes + 255) & ~(size_t)255;
        return r;
    };
    int* counter = (int*)alloc(4);
    int* deg     = (int*)alloc((size_t)N * 4);
    int* start   = (int*)alloc((size_t)N * 4);
    int* cursor  = (int*)alloc((size_t)N * 4);
    int* adj     = (int*)alloc((size_t)E * 4);
    ushort* wph  = (ushort*)alloc((size_t)139264 * 2);
    ushort* wpl  = (ushort*)alloc((size_t)139264 * 2);
    ushort* xp_h = (ushort*)alloc((size_t)N * 128 * 2);  // doubles as hBp_h
    ushort* xp_l = (ushort*)alloc((size_t)N * 128 * 2);  // doubles as hBp_l
    ushort* agg_h = (ushort*)alloc((size_t)N * 128 * 2);
    ushort* agg_l = (ushort*)alloc((size_t)N * 128 * 2);
    ushort* hA_h  = (ushort*)alloc((size_t)N * 128 * 2);
    ushort* hA_l  = (ushort*)alloc((size_t)N * 128 * 2);
    float*  hBf   = (float*)alloc((size_t)N * 128 * 4);

    hipMemsetAsync(d_ws, 0, (size_t)((char*)(deg + N) - (char*)d_ws), stream);

    const int gE = (E + 255) / 256;
    const int gN = (N + 255) / 256;
    const int gW = (N * 64 + 255) / 256;
    const int gX = (N * 16 + 255) / 256;
    const int gM = (N + 255) / 256;

    k_count <<<gE, 256, 0, stream>>>(ei, E, deg);
    k_starts<<<gN, 256, 0, stream>>>(deg, N, start, cursor, counter);
    k_fill  <<<gE, 256, 0, stream>>>(ei, E, cursor, adj);
    k_wpack <<<dim3(8, 9), 256, 0, stream>>>(wl, wr, wlin, wout, wph, wpl);
    k_splitx<<<gX, 256, 0, stream>>>(x, xp_h, xp_l, N);

    const ushort *wl0h = wph,             *wl0l = wpl;
    const ushort *wl1h = wph + 16384,     *wl1l = wpl + 16384;
    const ushort *wl2h = wph + 32768,     *wl2l = wpl + 32768;
    const ushort *wr0h = wph + 3*16384,   *wr0l = wpl + 3*16384;
    const ushort *wr1h = wph + 4*16384,   *wr1l = wpl + 4*16384;
    const ushort *wr2h = wph + 5*16384,   *wr2l = wpl + 5*16384;
    const ushort *wn0h = wph + 6*16384,   *wn0l = wpl + 6*16384;
    const ushort *wn1h = wph + 7*16384,   *wn1l = wpl + 7*16384;
    const ushort *woh  = wph + 8*16384,   *wol  = wpl + 8*16384;

    // layer 0
    k_agg<<<gW, 256, 0, stream>>>(x, adj, start, deg, agg_h, agg_l, N);
    k_gemm<128, true,  true,  true,  false><<<dim3(gM, 4), 256, 0, stream>>>(
        agg_h, agg_l, xp_h, xp_l, wl0h, wl0l, wr0h, wr0l, bc, hA_h, hA_l, nullptr, N);
    k_gemm<128, false, true,  true,  true ><<<dim3(gM, 4), 256, 0, stream>>>(
        hA_h, hA_l, nullptr, nullptr, wn0h, wn0l, nullptr, nullptr, blin, xp_h, xp_l, hBf, N);
    // layer 1
    k_agg<<<gW, 256, 0, stream>>>(hBf, adj, start, deg, agg_h, agg_l, N);
    k_gemm<128, true,  true,  true,  false><<<dim3(gM, 4), 256, 0, stream>>>(
        agg_h, agg_l, xp_h, xp_l, wl1h, wl1l, wr1h, wr1l, bc + 128, hA_h, hA_l, nullptr, N);
    k_gemm<128, false, true,  true,  true ><<<dim3(gM, 4), 256, 0, stream>>>(
        hA_h, hA_l, nullptr, nullptr, wn1h, wn1l, nullptr, nullptr, blin + 128, xp_h, xp_l, hBf, N);
    // layer 2 (no activation on conv)
    k_agg<<<gW, 256, 0, stream>>>(hBf, adj, start, deg, agg_h, agg_l, N);
    k_gemm<128, true,  false, true,  false><<<dim3(gM, 4), 256, 0, stream>>>(
        agg_h, agg_l, xp_h, xp_l, wl2h, wl2l, wr2h, wr2l, bc + 256, hA_h, hA_l, nullptr, N);
    // output projection (N=64, f32 out only)
    k_gemm<64,  false, false, false, true ><<<dim3(gM, 2), 256, 0, stream>>>(
        hA_h, hA_l, nullptr, nullptr, woh, wol, nullptr, nullptr, bout, nullptr, nullptr, out, N);
}

// Round 3
// 498.324 us; speedup vs baseline: 1.4051x; 1.0141x over previous
//
#include <hip/hip_runtime.h>

#define NEG_SLOPE 0.1f

typedef __bf16 bf16x8 __attribute__((ext_vector_type(8)));
typedef float f32x4 __attribute__((ext_vector_type(4)));
typedef unsigned int uint32x4 __attribute__((ext_vector_type(4)));
typedef unsigned short ushort;

__device__ inline ushort f2bf(float f) {
    unsigned int u = __float_as_uint(f);
    u += 0x7fffu + ((u >> 16) & 1u);
    return (ushort)(u >> 16);
}
__device__ inline float bf2f(ushort h) { return __uint_as_float(((unsigned int)h) << 16); }

__device__ inline void pack8(const float* v, uint32x4& hv, uint32x4& lv) {
    ushort hi[8], lo[8];
#pragma unroll
    for (int j = 0; j < 8; j++) {
        float f = v[j];
        ushort h = f2bf(f);
        hi[j] = h;
        lo[j] = f2bf(f - bf2f(h));
    }
    hv.x = hi[0] | ((unsigned)hi[1] << 16); hv.y = hi[2] | ((unsigned)hi[3] << 16);
    hv.z = hi[4] | ((unsigned)hi[5] << 16); hv.w = hi[6] | ((unsigned)hi[7] << 16);
    lv.x = lo[0] | ((unsigned)lo[1] << 16); lv.y = lo[2] | ((unsigned)lo[3] << 16);
    lv.z = lo[4] | ((unsigned)lo[5] << 16); lv.w = lo[6] | ((unsigned)lo[7] << 16);
}

// ---------------- CSR build ----------------

__global__ void k_count(const int* __restrict__ ei, int E, int* __restrict__ deg) {
    int e = blockIdx.x * 256 + threadIdx.x;
    if (e < E) atomicAdd(&deg[ei[E + e]], 1);
}

__global__ void k_starts(const int* __restrict__ deg, int N, int* __restrict__ start,
                         int* __restrict__ cursor, int* __restrict__ counter) {
    int n = blockIdx.x * 256 + threadIdx.x;
    int lane = threadIdx.x & 63;
    int d = (n < N) ? deg[n] : 0;
    int inc = d;
#pragma unroll
    for (int o = 1; o < 64; o <<= 1) {
        int v = __shfl_up(inc, o);
        if (lane >= o) inc += v;
    }
    int total = __shfl(inc, 63);
    int base = 0;
    if (lane == 0) base = atomicAdd(counter, total);
    base = __shfl(base, 0);
    int st = base + inc - d;
    if (n < N) { start[n] = st; cursor[n] = st; }
}

__global__ void k_fill(const int* __restrict__ ei, int E, int* __restrict__ cursor,
                       int* __restrict__ adj) {
    int e = blockIdx.x * 256 + threadIdx.x;
    if (e < E) {
        int s = ei[e];
        int dv = ei[E + e];
        int p = atomicAdd(&cursor[dv], 1);
        adj[p] = s;
    }
}

// ---------------- weight pre-pack: W[K][Nn] f32 -> packed hi/lo bf16 ----------------
// packed layout: [Nn/16 cb][16 kg][16 col][8 k]

__global__ __launch_bounds__(256) void k_wpack(const float* __restrict__ wl,
                                               const float* __restrict__ wr,
                                               const float* __restrict__ wlin,
                                               const float* __restrict__ wout,
                                               ushort* __restrict__ wph,
                                               ushort* __restrict__ wpl) {
    int m = blockIdx.y;
    int c = blockIdx.x * 256 + threadIdx.x;
    const float* src;
    int Nn = 128;
    size_t dstoff;
    if (m < 3)      { src = wl   + (size_t)m * 16384;       dstoff = (size_t)m * 16384; }
    else if (m < 6) { src = wr   + (size_t)(m - 3) * 16384; dstoff = (size_t)m * 16384; }
    else if (m < 8) { src = wlin + (size_t)(m - 6) * 16384; dstoff = (size_t)m * 16384; }
    else            { src = wout; Nn = 64;                  dstoff = (size_t)8 * 16384; }
    if (c >= Nn * 16) return;
    int cb = c >> 8, gg = (c >> 4) & 15, col = c & 15;
    float v[8];
#pragma unroll
    for (int j = 0; j < 8; j++)
        v[j] = src[(size_t)(gg * 8 + j) * Nn + cb * 16 + col];
    uint32x4 hv, lv;
    pack8(v, hv, lv);
    *(uint32x4*)(wph + dstoff + (size_t)c * 8) = hv;
    *(uint32x4*)(wpl + dstoff + (size_t)c * 8) = lv;
}

// ---------------- x f32 -> packed hi/lo ----------------

__global__ __launch_bounds__(256) void k_splitx(const float* __restrict__ x,
                                                ushort* __restrict__ oh,
                                                ushort* __restrict__ ol, int N) {
    int t = blockIdx.x * 256 + threadIdx.x;
    int row = t >> 4, g = t & 15;
    if (row >= N) return;
    const float* src = x + (size_t)row * 128 + g * 8;
    float v[8];
#pragma unroll
    for (int j = 0; j < 8; j++) v[j] = src[j];
    uint32x4 hv, lv;
    pack8(v, hv, lv);
    size_t off = ((size_t)(row >> 4) * 16 + g) * 128 + (row & 15) * 8;
    *(uint32x4*)(oh + off) = hv;
    *(uint32x4*)(ol + off) = lv;
}

// ---------------- mean aggregation: quarter-wave (16 lanes) per node ----------------
// lane q owns cols q*8..q*8+7 (= one packed chunk). 4 edges/iter -> 8 float4 in flight.

__global__ __launch_bounds__(256) void k_agg(const float* __restrict__ xf,
                                             const int* __restrict__ adj,
                                             const int* __restrict__ start,
                                             const int* __restrict__ deg,
                                             ushort* __restrict__ oh,
                                             ushort* __restrict__ ol, int N) {
    int node = (blockIdx.x * 256 + threadIdx.x) >> 4;
    if (node >= N) return;
    const int q = threadIdx.x & 15;
    const int st = start[node], cnt = deg[node];
    float c0x = 0, c0y = 0, c0z = 0, c0w = 0, c1x = 0, c1y = 0, c1z = 0, c1w = 0;
    int i = 0;
    for (; i + 4 <= cnt; i += 4) {
        int s0 = adj[st + i], s1 = adj[st + i + 1], s2 = adj[st + i + 2], s3 = adj[st + i + 3];
        const float* r0 = xf + ((size_t)s0 << 7) + (q << 3);
        const float* r1 = xf + ((size_t)s1 << 7) + (q << 3);
        const float* r2 = xf + ((size_t)s2 << 7) + (q << 3);
        const float* r3 = xf + ((size_t)s3 << 7) + (q << 3);
        float4 u0 = *(const float4*)r0, u1 = *(const float4*)(r0 + 4);
        float4 u2 = *(const float4*)r1, u3 = *(const float4*)(r1 + 4);
        float4 u4 = *(const float4*)r2, u5 = *(const float4*)(r2 + 4);
        float4 u6 = *(const float4*)r3, u7 = *(const float4*)(r3 + 4);
        c0x += u0.x + u2.x + u4.x + u6.x;
        c0y += u0.y + u2.y + u4.y + u6.y;
        c0z += u0.z + u2.z + u4.z + u6.z;
        c0w += u0.w + u2.w + u4.w + u6.w;
        c1x += u1.x + u3.x + u5.x + u7.x;
        c1y += u1.y + u3.y + u5.y + u7.y;
        c1z += u1.z + u3.z + u5.z + u7.z;
        c1w += u1.w + u3.w + u5.w + u7.w;
    }
    for (; i < cnt; i++) {
        int s0 = adj[st + i];
        const float* r0 = xf + ((size_t)s0 << 7) + (q << 3);
        float4 u0 = *(const float4*)r0, u1 = *(const float4*)(r0 + 4);
        c0x += u0.x; c0y += u0.y; c0z += u0.z; c0w += u0.w;
        c1x += u1.x; c1y += u1.y; c1z += u1.z; c1w += u1.w;
    }
    float inv = 1.0f / fmaxf((float)cnt, 1.0f);
    float v[8] = {c0x * inv, c0y * inv, c0z * inv, c0w * inv,
                  c1x * inv, c1y * inv, c1z * inv, c1w * inv};
    uint32x4 hv, lv;
    pack8(v, hv, lv);
    size_t off = ((size_t)(node >> 4) * 16 + q) * 128 + (node & 15) * 8;
    *(uint32x4*)(oh + off) = hv;
    *(uint32x4*)(ol + off) = lv;
}

// ---------------- split-bf16 MFMA GEMM, full-width blocks ----------------
// Block = 64 rows x NMAT cols; 4 waves = col quarters. Grid = ceil(M/64).
// A read ONCE per block (4 waves share via L1, kept lockstep by per-chunk barrier).

template <int NMAT, bool SECOND, bool ACT, bool WPACK, bool WF32>
__global__ __launch_bounds__(256) void k_gemm(
    const ushort* __restrict__ A1h, const ushort* __restrict__ A1l,
    const ushort* __restrict__ A2h, const ushort* __restrict__ A2l,
    const ushort* __restrict__ W1h, const ushort* __restrict__ W1l,
    const ushort* __restrict__ W2h, const ushort* __restrict__ W2l,
    const float* __restrict__ bias,
    ushort* __restrict__ Oph, ushort* __restrict__ Opl,
    float* __restrict__ Of32, int M) {
    constexpr int NCF = NMAT / 64;  // col fragments per wave (2 or 1)
    __shared__ float tile[WPACK ? 4 : 1][64][33];
    const int tid = threadIdx.x;
    const int w = tid >> 6, lane = tid & 63;
    const int g = lane >> 4, r16 = lane & 15;
    const int Mrb = (M + 15) >> 4;
    const int rb0 = blockIdx.x * 4;
    const int laneA = g * 128 + r16 * 8;

    f32x4 acc[4][NCF];
#pragma unroll
    for (int rf = 0; rf < 4; rf++)
#pragma unroll
        for (int cf = 0; cf < NCF; cf++) acc[rf][cf] = (f32x4){0.f, 0.f, 0.f, 0.f};

    for (int s = 0; s < 4; s++) {
        __syncthreads();  // keep waves on same A window for L1 reuse
        bf16x8 a1h[4], a1l[4], a2h[4], a2l[4];
#pragma unroll
        for (int rf = 0; rf < 4; rf++) {
            int rb = rb0 + rf;
            if (rb > Mrb - 1) rb = Mrb - 1;
            size_t off = (size_t)rb * 2048 + s * 512 + laneA;
            a1h[rf] = *(const bf16x8*)(A1h + off);
            a1l[rf] = *(const bf16x8*)(A1l + off);
            if constexpr (SECOND) {
                a2h[rf] = *(const bf16x8*)(A2h + off);
                a2l[rf] = *(const bf16x8*)(A2l + off);
            }
        }
        bf16x8 b1h[NCF], b1l[NCF], b2h[NCF], b2l[NCF];
#pragma unroll
        for (int cf = 0; cf < NCF; cf++) {
            size_t off = (size_t)(w * NCF + cf) * 2048 + s * 512 + laneA;
            b1h[cf] = *(const bf16x8*)(W1h + off);
            b1l[cf] = *(const bf16x8*)(W1l + off);
            if constexpr (SECOND) {
                b2h[cf] = *(const bf16x8*)(W2h + off);
                b2l[cf] = *(const bf16x8*)(W2l + off);
            }
        }
#pragma unroll
        for (int rf = 0; rf < 4; rf++)
#pragma unroll
            for (int cf = 0; cf < NCF; cf++)
                acc[rf][cf] = __builtin_amdgcn_mfma_f32_16x16x32_bf16(a1h[rf], b1h[cf], acc[rf][cf], 0, 0, 0);
#pragma unroll
        for (int rf = 0; rf < 4; rf++)
#pragma unroll
            for (int cf = 0; cf < NCF; cf++)
                acc[rf][cf] = __builtin_amdgcn_mfma_f32_16x16x32_bf16(a1h[rf], b1l[cf], acc[rf][cf], 0, 0, 0);
#pragma unroll
        for (int rf = 0; rf < 4; rf++)
#pragma unroll
            for (int cf = 0; cf < NCF; cf++)
                acc[rf][cf] = __builtin_amdgcn_mfma_f32_16x16x32_bf16(a1l[rf], b1h[cf], acc[rf][cf], 0, 0, 0);
        if constexpr (SECOND) {
#pragma unroll
            for (int rf = 0; rf < 4; rf++)
#pragma unroll
                for (int cf = 0; cf < NCF; cf++)
                    acc[rf][cf] = __builtin_amdgcn_mfma_f32_16x16x32_bf16(a2h[rf], b2h[cf], acc[rf][cf], 0, 0, 0);
#pragma unroll
            for (int rf = 0; rf < 4; rf++)
#pragma unroll
                for (int cf = 0; cf < NCF; cf++)
                    acc[rf][cf] = __builtin_amdgcn_mfma_f32_16x16x32_bf16(a2h[rf], b2l[cf], acc[rf][cf], 0, 0, 0);
#pragma unroll
            for (int rf = 0; rf < 4; rf++)
#pragma unroll
                for (int cf = 0; cf < NCF; cf++)
                    acc[rf][cf] = __builtin_amdgcn_mfma_f32_16x16x32_bf16(a2l[rf], b2h[cf], acc[rf][cf], 0, 0, 0);
        }
    }

    float bv[NCF];
#pragma unroll
    for (int cf = 0; cf < NCF; cf++) bv[cf] = bias[(w * NCF + cf) * 16 + r16];

    const int row_base = blockIdx.x * 64;
#pragma unroll
    for (int rf = 0; rf < 4; rf++)
#pragma unroll
        for (int cf = 0; cf < NCF; cf++)
#pragma unroll
            for (int i = 0; i < 4; i++) {
                float v = acc[rf][cf][i] + bv[cf];
                if (ACT) v = v > 0.f ? v : NEG_SLOPE * v;
                if constexpr (WPACK)
                    tile[w][rf * 16 + g * 4 + i][cf * 16 + r16] = v;
                if constexpr (WF32) {
                    int row = row_base + rf * 16 + g * 4 + i;
                    if (row < M)
                        Of32[(size_t)row * NMAT + (w * NCF + cf) * 16 + r16] = v;
                }
            }

    if constexpr (WPACK) {
        __syncthreads();
#pragma unroll
        for (int rep = 0; rep < 4; rep++) {
            int id = rep * 64 + lane;
            int rl = id >> 2, gl = id & 3;  // row-local 0..63, chunk-local 0..3
            int row = row_base + rl;
            if (row < M) {
                float v[8];
#pragma unroll
                for (int k = 0; k < 8; k++) v[k] = tile[w][rl][gl * 8 + k];
                uint32x4 hv, lv;
                pack8(v, hv, lv);
                int kg = w * 4 + gl;
                size_t off = ((size_t)(row >> 4) * 16 + kg) * 128 + (row & 15) * 8;
                *(uint32x4*)(Oph + off) = hv;
                *(uint32x4*)(Opl + off) = lv;
            }
        }
    }
}

// ---------------- launch ----------------

extern "C" void kernel_launch(void* const* d_in, const int* in_sizes, int n_in,
                              void* d_out, int out_size, void* d_ws, size_t ws_size,
                              hipStream_t stream) {
    const float* x    = (const float*)d_in[0];
    const int*   ei   = (const int*)d_in[1];
    const float* wl   = (const float*)d_in[2];
    const float* wr   = (const float*)d_in[3];
    const float* bc   = (const float*)d_in[4];
    const float* wlin = (const float*)d_in[5];
    const float* blin = (const float*)d_in[6];
    const float* wout = (const float*)d_in[7];
    const float* bout = (const float*)d_in[8];
    float* out = (float*)d_out;

    const int N = in_sizes[0] / 128;
    const int E = in_sizes[1] / 2;

    char* p = (char*)d_ws;
    auto alloc = [&](size_t bytes) {
        char* r = p;
        p += (bytes + 255) & ~(size_t)255;
        return r;
    };
    int* counter = (int*)alloc(4);
    int* deg     = (int*)alloc((size_t)N * 4);
    int* start   = (int*)alloc((size_t)N * 4);
    int* cursor  = (int*)alloc((size_t)N * 4);
    int* adj     = (int*)alloc((size_t)E * 4);
    ushort* wph  = (ushort*)alloc((size_t)139264 * 2);
    ushort* wpl  = (ushort*)alloc((size_t)139264 * 2);
    ushort* xp_h = (ushort*)alloc((size_t)N * 128 * 2);  // doubles as hBp_h
    ushort* xp_l = (ushort*)alloc((size_t)N * 128 * 2);  // doubles as hBp_l
    ushort* agg_h = (ushort*)alloc((size_t)N * 128 * 2);
    ushort* agg_l = (ushort*)alloc((size_t)N * 128 * 2);
    ushort* hA_h  = (ushort*)alloc((size_t)N * 128 * 2);
    ushort* hA_l  = (ushort*)alloc((size_t)N * 128 * 2);
    float*  hBf   = (float*)alloc((size_t)N * 128 * 4);

    hipMemsetAsync(d_ws, 0, (size_t)((char*)(deg + N) - (char*)d_ws), stream);

    const int gE = (E + 255) / 256;
    const int gN = (N + 255) / 256;
    const int gQ = (N * 16 + 255) / 256;  // quarter-wave per node
    const int gX = (N * 16 + 255) / 256;
    const int gB = (N + 63) / 64;         // full-width GEMM blocks

    k_count <<<gE, 256, 0, stream>>>(ei, E, deg);
    k_starts<<<gN, 256, 0, stream>>>(deg, N, start, cursor, counter);
    k_fill  <<<gE, 256, 0, stream>>>(ei, E, cursor, adj);
    k_wpack <<<dim3(8, 9), 256, 0, stream>>>(wl, wr, wlin, wout, wph, wpl);
    k_splitx<<<gX, 256, 0, stream>>>(x, xp_h, xp_l, N);

    const ushort *wl0h = wph,             *wl0l = wpl;
    const ushort *wl1h = wph + 16384,     *wl1l = wpl + 16384;
    const ushort *wl2h = wph + 32768,     *wl2l = wpl + 32768;
    const ushort *wr0h = wph + 3*16384,   *wr0l = wpl + 3*16384;
    const ushort *wr1h = wph + 4*16384,   *wr1l = wpl + 4*16384;
    const ushort *wr2h = wph + 5*16384,   *wr2l = wpl + 5*16384;
    const ushort *wn0h = wph + 6*16384,   *wn0l = wpl + 6*16384;
    const ushort *wn1h = wph + 7*16384,   *wn1l = wpl + 7*16384;
    const ushort *woh  = wph + 8*16384,   *wol  = wpl + 8*16384;

    // layer 0
    k_agg<<<gQ, 256, 0, stream>>>(x, adj, start, deg, agg_h, agg_l, N);
    k_gemm<128, true,  true,  true,  false><<<gB, 256, 0, stream>>>(
        agg_h, agg_l, xp_h, xp_l, wl0h, wl0l, wr0h, wr0l, bc, hA_h, hA_l, nullptr, N);
    k_gemm<128, false, true,  true,  true ><<<gB, 256, 0, stream>>>(
        hA_h, hA_l, nullptr, nullptr, wn0h, wn0l, nullptr, nullptr, blin, xp_h, xp_l, hBf, N);
    // layer 1
    k_agg<<<gQ, 256, 0, stream>>>(hBf, adj, start, deg, agg_h, agg_l, N);
    k_gemm<128, true,  true,  true,  false><<<gB, 256, 0, stream>>>(
        agg_h, agg_l, xp_h, xp_l, wl1h, wl1l, wr1h, wr1l, bc + 128, hA_h, hA_l, nullptr, N);
    k_gemm<128, false, true,  true,  true ><<<gB, 256, 0, stream>>>(
        hA_h, hA_l, nullptr, nullptr, wn1h, wn1l, nullptr, nullptr, blin + 128, xp_h, xp_l, hBf, N);
    // layer 2 (no activation on conv)
    k_agg<<<gQ, 256, 0, stream>>>(hBf, adj, start, deg, agg_h, agg_l, N);
    k_gemm<128, true,  false, true,  false><<<gB, 256, 0, stream>>>(
        agg_h, agg_l, xp_h, xp_l, wl2h, wl2l, wr2h, wr2l, bc + 256, hA_h, hA_l, nullptr, N);
    // output projection (NMAT=64, f32 out only)
    k_gemm<64,  false, false, false, true ><<<gB, 256, 0, stream>>>(
        hA_h, hA_l, nullptr, nullptr, woh, wol, nullptr, nullptr, bout, nullptr, nullptr, out, N);
}

// Round 4
// 415.392 us; speedup vs baseline: 1.6856x; 1.1996x over previous
//
#include <hip/hip_runtime.h>

#define NEG_SLOPE 0.1f

typedef __bf16 bf16x8 __attribute__((ext_vector_type(8)));
typedef float f32x4 __attribute__((ext_vector_type(4)));
typedef unsigned int uint32x4 __attribute__((ext_vector_type(4)));
typedef unsigned short ushort;

__device__ inline ushort f2bf(float f) {
    unsigned int u = __float_as_uint(f);
    u += 0x7fffu + ((u >> 16) & 1u);
    return (ushort)(u >> 16);
}
__device__ inline float bf2f(ushort h) { return __uint_as_float(((unsigned int)h) << 16); }

__device__ inline void pack8(const float* v, uint32x4& hv, uint32x4& lv) {
    ushort hi[8], lo[8];
#pragma unroll
    for (int j = 0; j < 8; j++) {
        float f = v[j];
        ushort h = f2bf(f);
        hi[j] = h;
        lo[j] = f2bf(f - bf2f(h));
    }
    hv.x = hi[0] | ((unsigned)hi[1] << 16); hv.y = hi[2] | ((unsigned)hi[3] << 16);
    hv.z = hi[4] | ((unsigned)hi[5] << 16); hv.w = hi[6] | ((unsigned)hi[7] << 16);
    lv.x = lo[0] | ((unsigned)lo[1] << 16); lv.y = lo[2] | ((unsigned)lo[3] << 16);
    lv.z = lo[4] | ((unsigned)lo[5] << 16); lv.w = lo[6] | ((unsigned)lo[7] << 16);
}

// ---------------- CSR build ----------------

__global__ void k_count(const int* __restrict__ ei, int E, int* __restrict__ deg) {
    int e = blockIdx.x * 256 + threadIdx.x;
    if (e < E) atomicAdd(&deg[ei[E + e]], 1);
}

__global__ void k_starts(const int* __restrict__ deg, int N, int* __restrict__ start,
                         int* __restrict__ cursor, int* __restrict__ counter) {
    int n = blockIdx.x * 256 + threadIdx.x;
    int lane = threadIdx.x & 63;
    int d = (n < N) ? deg[n] : 0;
    int inc = d;
#pragma unroll
    for (int o = 1; o < 64; o <<= 1) {
        int v = __shfl_up(inc, o);
        if (lane >= o) inc += v;
    }
    int total = __shfl(inc, 63);
    int base = 0;
    if (lane == 0) base = atomicAdd(counter, total);
    base = __shfl(base, 0);
    int st = base + inc - d;
    if (n < N) { start[n] = st; cursor[n] = st; }
}

__global__ void k_fill(const int* __restrict__ ei, int E, int* __restrict__ cursor,
                       int* __restrict__ adj) {
    int e = blockIdx.x * 256 + threadIdx.x;
    if (e < E) {
        int s = ei[e];
        int dv = ei[E + e];
        int p = atomicAdd(&cursor[dv], 1);
        adj[p] = s;
    }
}

// ---------------- weight pre-pack: W[K][Nn] f32 -> packed hi/lo bf16 ----------------
// packed layout: [Nn/16 cb][16 kg][16 col][8 k]

__global__ __launch_bounds__(256) void k_wpack(const float* __restrict__ wl,
                                               const float* __restrict__ wr,
                                               const float* __restrict__ wlin,
                                               const float* __restrict__ wout,
                                               ushort* __restrict__ wph,
                                               ushort* __restrict__ wpl) {
    int m = blockIdx.y;
    int c = blockIdx.x * 256 + threadIdx.x;
    const float* src;
    int Nn = 128;
    size_t dstoff;
    if (m < 3)      { src = wl   + (size_t)m * 16384;       dstoff = (size_t)m * 16384; }
    else if (m < 6) { src = wr   + (size_t)(m - 3) * 16384; dstoff = (size_t)m * 16384; }
    else if (m < 8) { src = wlin + (size_t)(m - 6) * 16384; dstoff = (size_t)m * 16384; }
    else            { src = wout; Nn = 64;                  dstoff = (size_t)8 * 16384; }
    if (c >= Nn * 16) return;
    int cb = c >> 8, gg = (c >> 4) & 15, col = c & 15;
    float v[8];
#pragma unroll
    for (int j = 0; j < 8; j++)
        v[j] = src[(size_t)(gg * 8 + j) * Nn + cb * 16 + col];
    uint32x4 hv, lv;
    pack8(v, hv, lv);
    *(uint32x4*)(wph + dstoff + (size_t)c * 8) = hv;
    *(uint32x4*)(wpl + dstoff + (size_t)c * 8) = lv;
}

// ---------------- x f32 -> row-major hi/lo bf16 ----------------

__global__ __launch_bounds__(256) void k_splitx(const float* __restrict__ x,
                                                ushort* __restrict__ oh,
                                                ushort* __restrict__ ol, int N) {
    int t = blockIdx.x * 256 + threadIdx.x;
    int row = t >> 4, g = t & 15;
    if (row >= N) return;
    const float* src = x + (size_t)row * 128 + g * 8;
    float v[8];
#pragma unroll
    for (int j = 0; j < 8; j++) v[j] = src[j];
    uint32x4 hv, lv;
    pack8(v, hv, lv);
    size_t off = (size_t)row * 128 + g * 8;
    *(uint32x4*)(oh + off) = hv;
    *(uint32x4*)(ol + off) = lv;
}

// ---------------- mean aggregation from bf16-hi rows ----------------
// quarter-wave (16 lanes) per node; lane q owns cols q*8..q*8+7 (16 B row chunk).

__global__ __launch_bounds__(256) void k_agg(const ushort* __restrict__ xh,
                                             const int* __restrict__ adj,
                                             const int* __restrict__ start,
                                             const int* __restrict__ deg,
                                             ushort* __restrict__ oh,
                                             ushort* __restrict__ ol, int N) {
    int node = (blockIdx.x * 256 + threadIdx.x) >> 4;
    if (node >= N) return;
    const int q = threadIdx.x & 15;
    const int st = start[node], cnt = deg[node];
    float a0 = 0, a1 = 0, a2 = 0, a3 = 0, a4 = 0, a5 = 0, a6 = 0, a7 = 0;
    int i = 0;
    for (; i + 4 <= cnt; i += 4) {
        int s0 = adj[st + i], s1 = adj[st + i + 1], s2 = adj[st + i + 2], s3 = adj[st + i + 3];
        uint32x4 u0 = *(const uint32x4*)(xh + (size_t)s0 * 128 + q * 8);
        uint32x4 u1 = *(const uint32x4*)(xh + (size_t)s1 * 128 + q * 8);
        uint32x4 u2 = *(const uint32x4*)(xh + (size_t)s2 * 128 + q * 8);
        uint32x4 u3 = *(const uint32x4*)(xh + (size_t)s3 * 128 + q * 8);
#pragma unroll
        for (int e = 0; e < 4; e++) {
            uint32x4 u = e == 0 ? u0 : e == 1 ? u1 : e == 2 ? u2 : u3;
            a0 += __uint_as_float(u.x << 16); a1 += __uint_as_float(u.x & 0xffff0000u);
            a2 += __uint_as_float(u.y << 16); a3 += __uint_as_float(u.y & 0xffff0000u);
            a4 += __uint_as_float(u.z << 16); a5 += __uint_as_float(u.z & 0xffff0000u);
            a6 += __uint_as_float(u.w << 16); a7 += __uint_as_float(u.w & 0xffff0000u);
        }
    }
    for (; i < cnt; i++) {
        int s0 = adj[st + i];
        uint32x4 u = *(const uint32x4*)(xh + (size_t)s0 * 128 + q * 8);
        a0 += __uint_as_float(u.x << 16); a1 += __uint_as_float(u.x & 0xffff0000u);
        a2 += __uint_as_float(u.y << 16); a3 += __uint_as_float(u.y & 0xffff0000u);
        a4 += __uint_as_float(u.z << 16); a5 += __uint_as_float(u.z & 0xffff0000u);
        a6 += __uint_as_float(u.w << 16); a7 += __uint_as_float(u.w & 0xffff0000u);
    }
    float inv = 1.0f / fmaxf((float)cnt, 1.0f);
    float v[8] = {a0 * inv, a1 * inv, a2 * inv, a3 * inv,
                  a4 * inv, a5 * inv, a6 * inv, a7 * inv};
    uint32x4 hv, lv;
    pack8(v, hv, lv);
    size_t off = (size_t)node * 128 + q * 8;
    *(uint32x4*)(oh + off) = hv;
    *(uint32x4*)(ol + off) = lv;
}

// ---------------- fused layer kernel ----------------
// Block = 64 rows x 128 cols, 4 waves (each 32 cols).
// Stage 1: conv = [act](agg@W1 + h@W2 + b1)  (split-bf16 MFMA, A from global rm)
// -> LDS f32 tile -> repack to LDS bf16 hi/lo ->
// Stage 2: out = [act](conv@W3 + b2) -> global rm hi/lo, or f32 d_out (FINAL).

template <bool ACT1, int NM2, bool ACT2, bool FINAL>
__global__ __launch_bounds__(256) void k_layer(
    const ushort* __restrict__ aggh, const ushort* __restrict__ aggl,
    const ushort* __restrict__ hh,   const ushort* __restrict__ hl,
    const ushort* __restrict__ w1h,  const ushort* __restrict__ w1l,
    const ushort* __restrict__ w2h,  const ushort* __restrict__ w2l,
    const float* __restrict__ b1,
    const ushort* __restrict__ w3h,  const ushort* __restrict__ w3l,
    const float* __restrict__ b2,
    ushort* __restrict__ oh, ushort* __restrict__ ol,
    float* __restrict__ of, int N) {
    constexpr int NCF2 = NM2 / 64;  // stage-2 col fragments per wave
    __shared__ float tile[4][32][33];        // half-height f32 staging
    __shared__ ushort th[64][136];           // conv result hi (row stride 136 = bank-tuned)
    __shared__ ushort tl[64][136];           // conv result lo

    const int tid = threadIdx.x;
    const int w = tid >> 6, lane = tid & 63;
    const int g = lane >> 4, r16 = lane & 15;
    const int m0 = blockIdx.x * 64;

    // per-rf clamped row offsets for A loads
    size_t ro[4];
#pragma unroll
    for (int rf = 0; rf < 4; rf++) {
        int row = m0 + rf * 16 + r16;
        if (row > N - 1) row = N - 1;
        ro[rf] = (size_t)row * 128 + g * 8;
    }

    // ---------------- stage 1: conv dual-GEMM ----------------
    f32x4 acc[4][2];
#pragma unroll
    for (int rf = 0; rf < 4; rf++)
#pragma unroll
        for (int cf = 0; cf < 2; cf++) acc[rf][cf] = (f32x4){0.f, 0.f, 0.f, 0.f};

#pragma unroll
    for (int s = 0; s < 4; s++) {
        bf16x8 a1h_[4], a1l_[4], a2h_[4], a2l_[4];
#pragma unroll
        for (int rf = 0; rf < 4; rf++) {
            size_t o = ro[rf] + s * 32;
            a1h_[rf] = *(const bf16x8*)(aggh + o);
            a1l_[rf] = *(const bf16x8*)(aggl + o);
            a2h_[rf] = *(const bf16x8*)(hh + o);
            a2l_[rf] = *(const bf16x8*)(hl + o);
        }
        bf16x8 b1h_[2], b1l_[2], b2h_[2], b2l_[2];
#pragma unroll
        for (int cf = 0; cf < 2; cf++) {
            size_t o = (size_t)(w * 2 + cf) * 2048 + s * 512 + g * 128 + r16 * 8;
            b1h_[cf] = *(const bf16x8*)(w1h + o);
            b1l_[cf] = *(const bf16x8*)(w1l + o);
            b2h_[cf] = *(const bf16x8*)(w2h + o);
            b2l_[cf] = *(const bf16x8*)(w2l + o);
        }
#pragma unroll
        for (int rf = 0; rf < 4; rf++)
#pragma unroll
            for (int cf = 0; cf < 2; cf++) {
                acc[rf][cf] = __builtin_amdgcn_mfma_f32_16x16x32_bf16(a1h_[rf], b1h_[cf], acc[rf][cf], 0, 0, 0);
                acc[rf][cf] = __builtin_amdgcn_mfma_f32_16x16x32_bf16(a1h_[rf], b1l_[cf], acc[rf][cf], 0, 0, 0);
                acc[rf][cf] = __builtin_amdgcn_mfma_f32_16x16x32_bf16(a1l_[rf], b1h_[cf], acc[rf][cf], 0, 0, 0);
                acc[rf][cf] = __builtin_amdgcn_mfma_f32_16x16x32_bf16(a2h_[rf], b2h_[cf], acc[rf][cf], 0, 0, 0);
                acc[rf][cf] = __builtin_amdgcn_mfma_f32_16x16x32_bf16(a2h_[rf], b2l_[cf], acc[rf][cf], 0, 0, 0);
                acc[rf][cf] = __builtin_amdgcn_mfma_f32_16x16x32_bf16(a2l_[rf], b2h_[cf], acc[rf][cf], 0, 0, 0);
            }
    }

    // ---------------- epilogue 1: bias/act -> f32 tile -> repack to th/tl ----------------
    float bv1[2];
#pragma unroll
    for (int cf = 0; cf < 2; cf++) bv1[cf] = b1[(w * 2 + cf) * 16 + r16];

#pragma unroll
    for (int half = 0; half < 2; half++) {
        __syncthreads();
#pragma unroll
        for (int rr = 0; rr < 2; rr++) {
            int rf = half * 2 + rr;
#pragma unroll
            for (int cf = 0; cf < 2; cf++)
#pragma unroll
                for (int i = 0; i < 4; i++) {
                    float v = acc[rf][cf][i] + bv1[cf];
                    if (ACT1) v = v > 0.f ? v : NEG_SLOPE * v;
                    tile[w][rr * 16 + g * 4 + i][cf * 16 + r16] = v;
                }
        }
        __syncthreads();
#pragma unroll
        for (int rep = 0; rep < 2; rep++) {
            int id = rep * 256 + tid;          // 0..511
            int row = id & 31, kg = id >> 5;   // row-in-half, chunk 0..15
            float v8[8];
#pragma unroll
            for (int j = 0; j < 8; j++) v8[j] = tile[kg >> 2][row][(kg & 3) * 8 + j];
            uint32x4 hv, lv;
            pack8(v8, hv, lv);
            int grow = half * 32 + row;
            *(uint32x4*)&th[grow][kg * 8] = hv;
            *(uint32x4*)&tl[grow][kg * 8] = lv;
        }
    }
    __syncthreads();

    // ---------------- stage 2: out GEMM (A from LDS th/tl) ----------------
    f32x4 acc2[4][NCF2];
#pragma unroll
    for (int rf = 0; rf < 4; rf++)
#pragma unroll
        for (int cf = 0; cf < NCF2; cf++) acc2[rf][cf] = (f32x4){0.f, 0.f, 0.f, 0.f};

#pragma unroll
    for (int s = 0; s < 4; s++) {
        bf16x8 ah_[4], al_[4];
#pragma unroll
        for (int rf = 0; rf < 4; rf++) {
            ah_[rf] = *(const bf16x8*)&th[rf * 16 + r16][s * 32 + g * 8];
            al_[rf] = *(const bf16x8*)&tl[rf * 16 + r16][s * 32 + g * 8];
        }
        bf16x8 wh_[NCF2], wlo_[NCF2];
#pragma unroll
        for (int cf = 0; cf < NCF2; cf++) {
            size_t o = (size_t)(w * NCF2 + cf) * 2048 + s * 512 + g * 128 + r16 * 8;
            wh_[cf] = *(const bf16x8*)(w3h + o);
            wlo_[cf] = *(const bf16x8*)(w3l + o);
        }
#pragma unroll
        for (int rf = 0; rf < 4; rf++)
#pragma unroll
            for (int cf = 0; cf < NCF2; cf++) {
                acc2[rf][cf] = __builtin_amdgcn_mfma_f32_16x16x32_bf16(ah_[rf], wh_[cf], acc2[rf][cf], 0, 0, 0);
                acc2[rf][cf] = __builtin_amdgcn_mfma_f32_16x16x32_bf16(ah_[rf], wlo_[cf], acc2[rf][cf], 0, 0, 0);
                acc2[rf][cf] = __builtin_amdgcn_mfma_f32_16x16x32_bf16(al_[rf], wh_[cf], acc2[rf][cf], 0, 0, 0);
            }
    }

    // ---------------- epilogue 2 ----------------
    if constexpr (FINAL) {
        // direct f32 store: col = w*16+r16, rows rf*16+g*4+i
        float bv2 = b2[w * 16 + r16];
#pragma unroll
        for (int rf = 0; rf < 4; rf++)
#pragma unroll
            for (int i = 0; i < 4; i++) {
                int row = m0 + rf * 16 + g * 4 + i;
                if (row < N) of[(size_t)row * 64 + w * 16 + r16] = acc2[rf][0][i] + bv2;
            }
    } else {
        float bv2[2];
#pragma unroll
        for (int cf = 0; cf < 2; cf++) bv2[cf] = b2[(w * 2 + cf) * 16 + r16];
#pragma unroll
        for (int half = 0; half < 2; half++) {
            __syncthreads();
#pragma unroll
            for (int rr = 0; rr < 2; rr++) {
                int rf = half * 2 + rr;
#pragma unroll
                for (int cf = 0; cf < 2; cf++)
#pragma unroll
                    for (int i = 0; i < 4; i++) {
                        float v = acc2[rf][cf][i] + bv2[cf];
                        if (ACT2) v = v > 0.f ? v : NEG_SLOPE * v;
                        tile[w][rr * 16 + g * 4 + i][cf * 16 + r16] = v;
                    }
            }
            __syncthreads();
            // coalesced global rm write: 16 consecutive lanes cover one row
#pragma unroll
            for (int rep = 0; rep < 2; rep++) {
                int row = (tid >> 4) + rep * 16;   // 0..31
                int kg = tid & 15;
                float v8[8];
#pragma unroll
                for (int j = 0; j < 8; j++) v8[j] = tile[kg >> 2][row][(kg & 3) * 8 + j];
                uint32x4 hv, lv;
                pack8(v8, hv, lv);
                int grow = m0 + half * 32 + row;
                if (grow < N) {
                    *(uint32x4*)(oh + (size_t)grow * 128 + kg * 8) = hv;
                    *(uint32x4*)(ol + (size_t)grow * 128 + kg * 8) = lv;
                }
            }
        }
    }
}

// ---------------- launch ----------------

extern "C" void kernel_launch(void* const* d_in, const int* in_sizes, int n_in,
                              void* d_out, int out_size, void* d_ws, size_t ws_size,
                              hipStream_t stream) {
    const float* x    = (const float*)d_in[0];
    const int*   ei   = (const int*)d_in[1];
    const float* wl   = (const float*)d_in[2];
    const float* wr   = (const float*)d_in[3];
    const float* bc   = (const float*)d_in[4];
    const float* wlin = (const float*)d_in[5];
    const float* blin = (const float*)d_in[6];
    const float* wout = (const float*)d_in[7];
    const float* bout = (const float*)d_in[8];
    float* out = (float*)d_out;

    const int N = in_sizes[0] / 128;
    const int E = in_sizes[1] / 2;

    char* p = (char*)d_ws;
    auto alloc = [&](size_t bytes) {
        char* r = p;
        p += (bytes + 255) & ~(size_t)255;
        return r;
    };
    int* counter = (int*)alloc(4);
    int* deg     = (int*)alloc((size_t)N * 4);
    int* start   = (int*)alloc((size_t)N * 4);
    int* cursor  = (int*)alloc((size_t)N * 4);
    int* adj     = (int*)alloc((size_t)E * 4);
    ushort* wph  = (ushort*)alloc((size_t)139264 * 2);
    ushort* wpl  = (ushort*)alloc((size_t)139264 * 2);
    ushort* xh   = (ushort*)alloc((size_t)N * 128 * 2);  // reused as layer-1 output
    ushort* xl   = (ushort*)alloc((size_t)N * 128 * 2);
    ushort* aggh = (ushort*)alloc((size_t)N * 128 * 2);
    ushort* aggl = (ushort*)alloc((size_t)N * 128 * 2);
    ushort* hAh  = (ushort*)alloc((size_t)N * 128 * 2);  // layer-0 output
    ushort* hAl  = (ushort*)alloc((size_t)N * 128 * 2);

    hipMemsetAsync(d_ws, 0, (size_t)((char*)(deg + N) - (char*)d_ws), stream);

    const int gE = (E + 255) / 256;
    const int gN = (N + 255) / 256;
    const int gQ = (N * 16 + 255) / 256;  // quarter-wave per node
    const int gB = (N + 63) / 64;         // layer blocks

    k_count <<<gE, 256, 0, stream>>>(ei, E, deg);
    k_starts<<<gN, 256, 0, stream>>>(deg, N, start, cursor, counter);
    k_fill  <<<gE, 256, 0, stream>>>(ei, E, cursor, adj);
    k_wpack <<<dim3(8, 9), 256, 0, stream>>>(wl, wr, wlin, wout, wph, wpl);
    k_splitx<<<gQ, 256, 0, stream>>>(x, xh, xl, N);

    const ushort *wl0h = wph,           *wl0l = wpl;
    const ushort *wl1h = wph + 16384,   *wl1l = wpl + 16384;
    const ushort *wl2h = wph + 32768,   *wl2l = wpl + 32768;
    const ushort *wr0h = wph + 3*16384, *wr0l = wpl + 3*16384;
    const ushort *wr1h = wph + 4*16384, *wr1l = wpl + 4*16384;
    const ushort *wr2h = wph + 5*16384, *wr2l = wpl + 5*16384;
    const ushort *wn0h = wph + 6*16384, *wn0l = wpl + 6*16384;
    const ushort *wn1h = wph + 7*16384, *wn1l = wpl + 7*16384;
    const ushort *woh  = wph + 8*16384, *wol  = wpl + 8*16384;

    // layer 0: agg(x) ; h = x
    k_agg<<<gQ, 256, 0, stream>>>(xh, adj, start, deg, aggh, aggl, N);
    k_layer<true, 128, true, false><<<gB, 256, 0, stream>>>(
        aggh, aggl, xh, xl, wl0h, wl0l, wr0h, wr0l, bc,
        wn0h, wn0l, blin, hAh, hAl, nullptr, N);
    // layer 1: agg(hA) ; h = hA -> writes xh/xl (x dead)
    k_agg<<<gQ, 256, 0, stream>>>(hAh, adj, start, deg, aggh, aggl, N);
    k_layer<true, 128, true, false><<<gB, 256, 0, stream>>>(
        aggh, aggl, hAh, hAl, wl1h, wl1l, wr1h, wr1l, bc + 128,
        wn1h, wn1l, blin + 128, xh, xl, nullptr, N);
    // layer 2: agg(x') ; conv (no act) + wout projection -> d_out
    k_agg<<<gQ, 256, 0, stream>>>(xh, adj, start, deg, aggh, aggl, N);
    k_layer<false, 64, false, true><<<gB, 256, 0, stream>>>(
        aggh, aggl, xh, xl, wl2h, wl2l, wr2h, wr2l, bc + 256,
        woh, wol, bout, nullptr, nullptr, out, N);
}

// Round 7
// 364.790 us; speedup vs baseline: 1.9194x; 1.1387x over previous
//
#include <hip/hip_runtime.h>

#define NEG_SLOPE 0.1f

typedef __bf16 bf16x8 __attribute__((ext_vector_type(8)));
typedef float f32x4 __attribute__((ext_vector_type(4)));
typedef unsigned int uint32x4 __attribute__((ext_vector_type(4)));
typedef unsigned short ushort;

__device__ inline ushort f2bf(float f) {
    unsigned int u = __float_as_uint(f);
    u += 0x7fffu + ((u >> 16) & 1u);
    return (ushort)(u >> 16);
}
__device__ inline float bf2f(ushort h) { return __uint_as_float(((unsigned int)h) << 16); }

__device__ inline void pack8(const float* v, uint32x4& hv, uint32x4& lv) {
    ushort hi[8], lo[8];
#pragma unroll
    for (int j = 0; j < 8; j++) {
        float f = v[j];
        ushort h = f2bf(f);
        hi[j] = h;
        lo[j] = f2bf(f - bf2f(h));
    }
    hv.x = hi[0] | ((unsigned)hi[1] << 16); hv.y = hi[2] | ((unsigned)hi[3] << 16);
    hv.z = hi[4] | ((unsigned)hi[5] << 16); hv.w = hi[6] | ((unsigned)hi[7] << 16);
    lv.x = lo[0] | ((unsigned)lo[1] << 16); lv.y = lo[2] | ((unsigned)lo[3] << 16);
    lv.z = lo[4] | ((unsigned)lo[5] << 16); lv.w = lo[6] | ((unsigned)lo[7] << 16);
}

// ---------------- CSR build ----------------
// Pass 1: degree count (padded, 1 counter per 64B line) + per-edge rank (coalesced).
__global__ void k_count(const int* __restrict__ ei, int E, int* __restrict__ degp,
                        int* __restrict__ rank) {
    int e = blockIdx.x * 256 + threadIdx.x;
    if (e < E) rank[e] = atomicAdd(&degp[(size_t)ei[E + e] * 16], 1);
}

__global__ void k_starts(const int* __restrict__ degp, int N, int* __restrict__ start,
                         int* __restrict__ deg, int* __restrict__ counter) {
    int n = blockIdx.x * 256 + threadIdx.x;
    int lane = threadIdx.x & 63;
    int d = (n < N) ? degp[(size_t)n * 16] : 0;
    int inc = d;
#pragma unroll
    for (int o = 1; o < 64; o <<= 1) {
        int v = __shfl_up(inc, o);
        if (lane >= o) inc += v;
    }
    int total = __shfl(inc, 63);
    int base = 0;
    if (lane == 0) base = atomicAdd(counter, total);
    base = __shfl(base, 0);
    int st = base + inc - d;
    if (n < N) { start[n] = st; deg[n] = d; }
}

// Pass 3: atomic-free scatter.
__global__ void k_fill(const int* __restrict__ ei, int E, const int* __restrict__ start,
                       const int* __restrict__ rank, int* __restrict__ adj) {
    int e = blockIdx.x * 256 + threadIdx.x;
    if (e < E) {
        int s = ei[e];
        int dv = ei[E + e];
        adj[start[dv] + rank[e]] = s;
    }
}

// ---------------- weight pre-pack: W[K][Nn] f32 -> packed hi/lo bf16 ----------------
// packed layout: [Nn/16 cb][16 kg][16 col][8 k]

__global__ __launch_bounds__(256) void k_wpack(const float* __restrict__ wl,
                                               const float* __restrict__ wr,
                                               const float* __restrict__ wlin,
                                               const float* __restrict__ wout,
                                               ushort* __restrict__ wph,
                                               ushort* __restrict__ wpl) {
    int m = blockIdx.y;
    int c = blockIdx.x * 256 + threadIdx.x;
    const float* src;
    int Nn = 128;
    size_t dstoff;
    if (m < 3)      { src = wl   + (size_t)m * 16384;       dstoff = (size_t)m * 16384; }
    else if (m < 6) { src = wr   + (size_t)(m - 3) * 16384; dstoff = (size_t)m * 16384; }
    else if (m < 8) { src = wlin + (size_t)(m - 6) * 16384; dstoff = (size_t)m * 16384; }
    else            { src = wout; Nn = 64;                  dstoff = (size_t)8 * 16384; }
    if (c >= Nn * 16) return;
    int cb = c >> 8, gg = (c >> 4) & 15, col = c & 15;
    float v[8];
#pragma unroll
    for (int j = 0; j < 8; j++)
        v[j] = src[(size_t)(gg * 8 + j) * Nn + cb * 16 + col];
    uint32x4 hv, lv;
    pack8(v, hv, lv);
    *(uint32x4*)(wph + dstoff + (size_t)c * 8) = hv;
    *(uint32x4*)(wpl + dstoff + (size_t)c * 8) = lv;
}

// ---------------- x f32 -> row-major hi/lo bf16 ----------------

__global__ __launch_bounds__(256) void k_splitx(const float* __restrict__ x,
                                                ushort* __restrict__ oh,
                                                ushort* __restrict__ ol, int N) {
    int t = blockIdx.x * 256 + threadIdx.x;
    int row = t >> 4, g = t & 15;
    if (row >= N) return;
    const float* src = x + (size_t)row * 128 + g * 8;
    float v[8];
#pragma unroll
    for (int j = 0; j < 8; j++) v[j] = src[j];
    uint32x4 hv, lv;
    pack8(v, hv, lv);
    size_t off = (size_t)row * 128 + g * 8;
    *(uint32x4*)(oh + off) = hv;
    *(uint32x4*)(ol + off) = lv;
}

// ---------------- mean aggregation from bf16-hi rows ----------------
// quarter-wave (16 lanes) per node; lane q owns cols q*8..q*8+7 (16 B row chunk).

__global__ __launch_bounds__(256) void k_agg(const ushort* __restrict__ xh,
                                             const int* __restrict__ adj,
                                             const int* __restrict__ start,
                                             const int* __restrict__ deg,
                                             ushort* __restrict__ oh,
                                             ushort* __restrict__ ol, int N) {
    int node = (blockIdx.x * 256 + threadIdx.x) >> 4;
    if (node >= N) return;
    const int q = threadIdx.x & 15;
    const int st = start[node], cnt = deg[node];
    float a0 = 0, a1 = 0, a2 = 0, a3 = 0, a4 = 0, a5 = 0, a6 = 0, a7 = 0;
    int i = 0;
    for (; i + 4 <= cnt; i += 4) {
        int s0 = adj[st + i], s1 = adj[st + i + 1], s2 = adj[st + i + 2], s3 = adj[st + i + 3];
        uint32x4 u0 = *(const uint32x4*)(xh + (size_t)s0 * 128 + q * 8);
        uint32x4 u1 = *(const uint32x4*)(xh + (size_t)s1 * 128 + q * 8);
        uint32x4 u2 = *(const uint32x4*)(xh + (size_t)s2 * 128 + q * 8);
        uint32x4 u3 = *(const uint32x4*)(xh + (size_t)s3 * 128 + q * 8);
#pragma unroll
        for (int e = 0; e < 4; e++) {
            uint32x4 u = e == 0 ? u0 : e == 1 ? u1 : e == 2 ? u2 : u3;
            a0 += __uint_as_float(u.x << 16); a1 += __uint_as_float(u.x & 0xffff0000u);
            a2 += __uint_as_float(u.y << 16); a3 += __uint_as_float(u.y & 0xffff0000u);
            a4 += __uint_as_float(u.z << 16); a5 += __uint_as_float(u.z & 0xffff0000u);
            a6 += __uint_as_float(u.w << 16); a7 += __uint_as_float(u.w & 0xffff0000u);
        }
    }
    for (; i < cnt; i++) {
        int s0 = adj[st + i];
        uint32x4 u = *(const uint32x4*)(xh + (size_t)s0 * 128 + q * 8);
        a0 += __uint_as_float(u.x << 16); a1 += __uint_as_float(u.x & 0xffff0000u);
        a2 += __uint_as_float(u.y << 16); a3 += __uint_as_float(u.y & 0xffff0000u);
        a4 += __uint_as_float(u.z << 16); a5 += __uint_as_float(u.z & 0xffff0000u);
        a6 += __uint_as_float(u.w << 16); a7 += __uint_as_float(u.w & 0xffff0000u);
    }
    float inv = 1.0f / fmaxf((float)cnt, 1.0f);
    float v[8] = {a0 * inv, a1 * inv, a2 * inv, a3 * inv,
                  a4 * inv, a5 * inv, a6 * inv, a7 * inv};
    uint32x4 hv, lv;
    pack8(v, hv, lv);
    size_t off = (size_t)node * 128 + q * 8;
    *(uint32x4*)(oh + off) = hv;
    *(uint32x4*)(ol + off) = lv;
}

// ---------------- fused layer kernel ----------------
// Block = 64 rows x 128 cols, 4 waves (each a 32-col slice).
// Stage 1: conv = [act](agg@W1 + h@W2 + b1)  -> hi/lo direct 2B stores into LDS th/tl
// Stage 2: out = [act](conv@W3 + b2) -> global rm hi/lo (th/tl reused for the
// coalesced write staging), or f32 d_out directly (FINAL).

template <bool ACT1, int NM2, bool ACT2, bool FINAL>
__global__ __launch_bounds__(256) void k_layer(
    const ushort* __restrict__ aggh, const ushort* __restrict__ aggl,
    const ushort* __restrict__ hh,   const ushort* __restrict__ hl,
    const ushort* __restrict__ w1h,  const ushort* __restrict__ w1l,
    const ushort* __restrict__ w2h,  const ushort* __restrict__ w2l,
    const float* __restrict__ b1,
    const ushort* __restrict__ w3h,  const ushort* __restrict__ w3l,
    const float* __restrict__ b2,
    ushort* __restrict__ oh, ushort* __restrict__ ol,
    float* __restrict__ of, int N) {
    constexpr int NCF2 = NM2 / 64;  // stage-2 col fragments per wave
    __shared__ ushort th[64][136];  // conv result hi (stride 136: 272B rows)
    __shared__ ushort tl[64][136];  // conv result lo

    const int tid = threadIdx.x;
    const int w = tid >> 6, lane = tid & 63;
    const int g = lane >> 4, r16 = lane & 15;
    const int m0 = blockIdx.x * 64;

    // per-rf clamped row offsets for A loads
    size_t ro[4];
#pragma unroll
    for (int rf = 0; rf < 4; rf++) {
        int row = m0 + rf * 16 + r16;
        if (row > N - 1) row = N - 1;
        ro[rf] = (size_t)row * 128 + g * 8;
    }

    // ---------------- stage 1: conv dual-GEMM ----------------
    f32x4 acc[4][2];
#pragma unroll
    for (int rf = 0; rf < 4; rf++)
#pragma unroll
        for (int cf = 0; cf < 2; cf++) acc[rf][cf] = (f32x4){0.f, 0.f, 0.f, 0.f};

#pragma unroll
    for (int s = 0; s < 4; s++) {
        bf16x8 a1h_[4], a1l_[4], a2h_[4], a2l_[4];
#pragma unroll
        for (int rf = 0; rf < 4; rf++) {
            size_t o = ro[rf] + s * 32;
            a1h_[rf] = *(const bf16x8*)(aggh + o);
            a1l_[rf] = *(const bf16x8*)(aggl + o);
            a2h_[rf] = *(const bf16x8*)(hh + o);
            a2l_[rf] = *(const bf16x8*)(hl + o);
        }
        bf16x8 b1h_[2], b1l_[2], b2h_[2], b2l_[2];
#pragma unroll
        for (int cf = 0; cf < 2; cf++) {
            size_t o = (size_t)(w * 2 + cf) * 2048 + s * 512 + g * 128 + r16 * 8;
            b1h_[cf] = *(const bf16x8*)(w1h + o);
            b1l_[cf] = *(const bf16x8*)(w1l + o);
            b2h_[cf] = *(const bf16x8*)(w2h + o);
            b2l_[cf] = *(const bf16x8*)(w2l + o);
        }
#pragma unroll
        for (int rf = 0; rf < 4; rf++)
#pragma unroll
            for (int cf = 0; cf < 2; cf++) {
                acc[rf][cf] = __builtin_amdgcn_mfma_f32_16x16x32_bf16(a1h_[rf], b1h_[cf], acc[rf][cf], 0, 0, 0);
                acc[rf][cf] = __builtin_amdgcn_mfma_f32_16x16x32_bf16(a1h_[rf], b1l_[cf], acc[rf][cf], 0, 0, 0);
                acc[rf][cf] = __builtin_amdgcn_mfma_f32_16x16x32_bf16(a1l_[rf], b1h_[cf], acc[rf][cf], 0, 0, 0);
                acc[rf][cf] = __builtin_amdgcn_mfma_f32_16x16x32_bf16(a2h_[rf], b2h_[cf], acc[rf][cf], 0, 0, 0);
                acc[rf][cf] = __builtin_amdgcn_mfma_f32_16x16x32_bf16(a2h_[rf], b2l_[cf], acc[rf][cf], 0, 0, 0);
                acc[rf][cf] = __builtin_amdgcn_mfma_f32_16x16x32_bf16(a2l_[rf], b2h_[cf], acc[rf][cf], 0, 0, 0);
            }
    }

    // ---------------- epilogue 1: bias/act -> direct 2B hi/lo stores ----------------
    {
        float bv1[2];
#pragma unroll
        for (int cf = 0; cf < 2; cf++) bv1[cf] = b1[(w * 2 + cf) * 16 + r16];
#pragma unroll
        for (int rf = 0; rf < 4; rf++)
#pragma unroll
            for (int cf = 0; cf < 2; cf++)
#pragma unroll
                for (int i = 0; i < 4; i++) {
                    float v = acc[rf][cf][i] + bv1[cf];
                    if (ACT1) v = v > 0.f ? v : NEG_SLOPE * v;
                    ushort hi = f2bf(v);
                    ushort lo = f2bf(v - bf2f(hi));
                    th[rf * 16 + g * 4 + i][w * 32 + cf * 16 + r16] = hi;
                    tl[rf * 16 + g * 4 + i][w * 32 + cf * 16 + r16] = lo;
                }
    }
    __syncthreads();

    // ---------------- stage 2: out GEMM (A from LDS th/tl) ----------------
    f32x4 acc2[4][NCF2];
#pragma unroll
    for (int rf = 0; rf < 4; rf++)
#pragma unroll
        for (int cf = 0; cf < NCF2; cf++) acc2[rf][cf] = (f32x4){0.f, 0.f, 0.f, 0.f};

#pragma unroll
    for (int s = 0; s < 4; s++) {
        bf16x8 ah_[4], al_[4];
#pragma unroll
        for (int rf = 0; rf < 4; rf++) {
            ah_[rf] = *(const bf16x8*)&th[rf * 16 + r16][s * 32 + g * 8];
            al_[rf] = *(const bf16x8*)&tl[rf * 16 + r16][s * 32 + g * 8];
        }
        bf16x8 wh_[NCF2], wlo_[NCF2];
#pragma unroll
        for (int cf = 0; cf < NCF2; cf++) {
            size_t o = (size_t)(w * NCF2 + cf) * 2048 + s * 512 + g * 128 + r16 * 8;
            wh_[cf] = *(const bf16x8*)(w3h + o);
            wlo_[cf] = *(const bf16x8*)(w3l + o);
        }
#pragma unroll
        for (int rf = 0; rf < 4; rf++)
#pragma unroll
            for (int cf = 0; cf < NCF2; cf++) {
                acc2[rf][cf] = __builtin_amdgcn_mfma_f32_16x16x32_bf16(ah_[rf], wh_[cf], acc2[rf][cf], 0, 0, 0);
                acc2[rf][cf] = __builtin_amdgcn_mfma_f32_16x16x32_bf16(ah_[rf], wlo_[cf], acc2[rf][cf], 0, 0, 0);
                acc2[rf][cf] = __builtin_amdgcn_mfma_f32_16x16x32_bf16(al_[rf], wh_[cf], acc2[rf][cf], 0, 0, 0);
            }
    }

    // ---------------- epilogue 2 ----------------
    if constexpr (FINAL) {
        float bv2 = b2[w * 16 + r16];
#pragma unroll
        for (int rf = 0; rf < 4; rf++)
#pragma unroll
            for (int i = 0; i < 4; i++) {
                int row = m0 + rf * 16 + g * 4 + i;
                if (row < N) of[(size_t)row * 64 + w * 16 + r16] = acc2[rf][0][i] + bv2;
            }
    } else {
        __syncthreads();  // all stage-2 reads of th/tl done before reuse
        float bv2[2];
#pragma unroll
        for (int cf = 0; cf < 2; cf++) bv2[cf] = b2[(w * 2 + cf) * 16 + r16];
#pragma unroll
        for (int rf = 0; rf < 4; rf++)
#pragma unroll
            for (int cf = 0; cf < 2; cf++)
#pragma unroll
                for (int i = 0; i < 4; i++) {
                    float v = acc2[rf][cf][i] + bv2[cf];
                    if (ACT2) v = v > 0.f ? v : NEG_SLOPE * v;
                    ushort hi = f2bf(v);
                    ushort lo = f2bf(v - bf2f(hi));
                    th[rf * 16 + g * 4 + i][w * 32 + cf * 16 + r16] = hi;
                    tl[rf * 16 + g * 4 + i][w * 32 + cf * 16 + r16] = lo;
                }
        __syncthreads();
#pragma unroll
        for (int rep = 0; rep < 4; rep++) {
            int id = rep * 256 + tid;       // 0..1023
            int row = id >> 4, kg = id & 15;
            int grow = m0 + row;
            if (grow < N) {
                uint32x4 hv = *(const uint32x4*)&th[row][kg * 8];
                uint32x4 lv = *(const uint32x4*)&tl[row][kg * 8];
                *(uint32x4*)(oh + (size_t)grow * 128 + kg * 8) = hv;
                *(uint32x4*)(ol + (size_t)grow * 128 + kg * 8) = lv;
            }
        }
    }
}

// ---------------- launch ----------------

extern "C" void kernel_launch(void* const* d_in, const int* in_sizes, int n_in,
                              void* d_out, int out_size, void* d_ws, size_t ws_size,
                              hipStream_t stream) {
    const float* x    = (const float*)d_in[0];
    const int*   ei   = (const int*)d_in[1];
    const float* wl   = (const float*)d_in[2];
    const float* wr   = (const float*)d_in[3];
    const float* bc   = (const float*)d_in[4];
    const float* wlin = (const float*)d_in[5];
    const float* blin = (const float*)d_in[6];
    const float* wout = (const float*)d_in[7];
    const float* bout = (const float*)d_in[8];
    float* out = (float*)d_out;

    const int N = in_sizes[0] / 128;
    const int E = in_sizes[1] / 2;

    char* p = (char*)d_ws;
    auto alloc = [&](size_t bytes) {
        char* r = p;
        p += (bytes + 255) & ~(size_t)255;
        return r;
    };
    int* counter = (int*)alloc(4);
    int* degp    = (int*)alloc((size_t)N * 16 * 4);  // padded: 1 counter / 64B line
    int* deg     = (int*)alloc((size_t)N * 4);
    int* start   = (int*)alloc((size_t)N * 4);
    int* rank    = (int*)alloc((size_t)E * 4);
    int* adj     = (int*)alloc((size_t)E * 4);
    ushort* wph  = (ushort*)alloc((size_t)139264 * 2);
    ushort* wpl  = (ushort*)alloc((size_t)139264 * 2);
    ushort* xh   = (ushort*)alloc((size_t)N * 128 * 2);  // reused as layer-1 output
    ushort* xl   = (ushort*)alloc((size_t)N * 128 * 2);
    ushort* aggh = (ushort*)alloc((size_t)N * 128 * 2);
    ushort* aggl = (ushort*)alloc((size_t)N * 128 * 2);
    ushort* hAh  = (ushort*)alloc((size_t)N * 128 * 2);  // layer-0 output
    ushort* hAl  = (ushort*)alloc((size_t)N * 128 * 2);

    // zero counter + degp (contiguous at the front of ws)
    hipMemsetAsync(d_ws, 0, (size_t)((char*)(degp + (size_t)N * 16) - (char*)d_ws), stream);

    const int gE = (E + 255) / 256;
    const int gN = (N + 255) / 256;
    const int gQ = (N * 16 + 255) / 256;  // quarter-wave per node
    const int gB = (N + 63) / 64;         // layer blocks

    k_count <<<gE, 256, 0, stream>>>(ei, E, degp, rank);
    k_starts<<<gN, 256, 0, stream>>>(degp, N, start, deg, counter);
    k_fill  <<<gE, 256, 0, stream>>>(ei, E, start, rank, adj);
    k_wpack <<<dim3(8, 9), 256, 0, stream>>>(wl, wr, wlin, wout, wph, wpl);
    k_splitx<<<gQ, 256, 0, stream>>>(x, xh, xl, N);

    const ushort *wl0h = wph,           *wl0l = wpl;
    const ushort *wl1h = wph + 16384,   *wl1l = wpl + 16384;
    const ushort *wl2h = wph + 32768,   *wl2l = wpl + 32768;
    const ushort *wr0h = wph + 3*16384, *wr0l = wpl + 3*16384;
    const ushort *wr1h = wph + 4*16384, *wr1l = wpl + 4*16384;
    const ushort *wr2h = wph + 5*16384, *wr2l = wpl + 5*16384;
    const ushort *wn0h = wph + 6*16384, *wn0l = wpl + 6*16384;
    const ushort *wn1h = wph + 7*16384, *wn1l = wpl + 7*16384;
    const ushort *woh  = wph + 8*16384, *wol  = wpl + 8*16384;

    // layer 0: agg(x) ; h = x
    k_agg<<<gQ, 256, 0, stream>>>(xh, adj, start, deg, aggh, aggl, N);
    k_layer<true, 128, true, false><<<gB, 256, 0, stream>>>(
        aggh, aggl, xh, xl, wl0h, wl0l, wr0h, wr0l, bc,
        wn0h, wn0l, blin, hAh, hAl, nullptr, N);
    // layer 1: agg(hA) ; h = hA -> writes xh/xl (x dead)
    k_agg<<<gQ, 256, 0, stream>>>(hAh, adj, start, deg, aggh, aggl, N);
    k_layer<true, 128, true, false><<<gB, 256, 0, stream>>>(
        aggh, aggl, hAh, hAl, wl1h, wl1l, wr1h, wr1l, bc + 128,
        wn1h, wn1l, blin + 128, xh, xl, nullptr, N);
    // layer 2: agg(x') ; conv (no act) + wout projection -> d_out
    k_agg<<<gQ, 256, 0, stream>>>(xh, adj, start, deg, aggh, aggl, N);
    k_layer<false, 64, false, true><<<gB, 256, 0, stream>>>(
        aggh, aggl, xh, xl, wl2h, wl2l, wr2h, wr2l, bc + 256,
        woh, wol, bout, nullptr, nullptr, out, N);
}

// Round 9
// 323.034 us; speedup vs baseline: 2.1675x; 1.1293x over previous
//
#include <hip/hip_runtime.h>

#define NEG_SLOPE 0.1f

typedef __bf16 bf16x8 __attribute__((ext_vector_type(8)));
typedef float f32x4 __attribute__((ext_vector_type(4)));
typedef unsigned int uint32x4 __attribute__((ext_vector_type(4)));
typedef unsigned short ushort;

__device__ inline ushort f2bf(float f) {
    unsigned int u = __float_as_uint(f);
    u += 0x7fffu + ((u >> 16) & 1u);
    return (ushort)(u >> 16);
}
__device__ inline float bf2f(ushort h) { return __uint_as_float(((unsigned int)h) << 16); }

__device__ inline void pack8(const float* v, uint32x4& hv, uint32x4& lv) {
    ushort hi[8], lo[8];
#pragma unroll
    for (int j = 0; j < 8; j++) {
        float f = v[j];
        ushort h = f2bf(f);
        hi[j] = h;
        lo[j] = f2bf(f - bf2f(h));
    }
    hv.x = hi[0] | ((unsigned)hi[1] << 16); hv.y = hi[2] | ((unsigned)hi[3] << 16);
    hv.z = hi[4] | ((unsigned)hi[5] << 16); hv.w = hi[6] | ((unsigned)hi[7] << 16);
    lv.x = lo[0] | ((unsigned)lo[1] << 16); lv.y = lo[2] | ((unsigned)lo[3] << 16);
    lv.z = lo[4] | ((unsigned)lo[5] << 16); lv.w = lo[6] | ((unsigned)lo[7] << 16);
}

// ---------------- CSR build ----------------
// Pass 1: degree count (padded, 1 counter per 64B line) + per-edge rank (coalesced).
__global__ void k_count(const int* __restrict__ ei, int E, int* __restrict__ degp,
                        int* __restrict__ rank) {
    int e = blockIdx.x * 256 + threadIdx.x;
    if (e < E) rank[e] = atomicAdd(&degp[(size_t)ei[E + e] * 16], 1);
}

__global__ void k_starts(const int* __restrict__ degp, int N, int* __restrict__ start,
                         int* __restrict__ deg, int* __restrict__ counter) {
    int n = blockIdx.x * 256 + threadIdx.x;
    int lane = threadIdx.x & 63;
    int d = (n < N) ? degp[(size_t)n * 16] : 0;
    int inc = d;
#pragma unroll
    for (int o = 1; o < 64; o <<= 1) {
        int v = __shfl_up(inc, o);
        if (lane >= o) inc += v;
    }
    int total = __shfl(inc, 63);
    int base = 0;
    if (lane == 0) base = atomicAdd(counter, total);
    base = __shfl(base, 0);
    int st = base + inc - d;
    if (n < N) { start[n] = st; deg[n] = d; }
}

// Pass 3: atomic-free scatter.
__global__ void k_fill(const int* __restrict__ ei, int E, const int* __restrict__ start,
                       const int* __restrict__ rank, int* __restrict__ adj) {
    int e = blockIdx.x * 256 + threadIdx.x;
    if (e < E) {
        int s = ei[e];
        int dv = ei[E + e];
        adj[start[dv] + rank[e]] = s;
    }
}

// ---------------- weight pre-pack: W[K][Nn] f32 -> packed hi/lo bf16 ----------------
// packed layout: [Nn/16 cb][16 kg][16 col][8 k]

__global__ __launch_bounds__(256) void k_wpack(const float* __restrict__ wl,
                                               const float* __restrict__ wr,
                                               const float* __restrict__ wlin,
                                               const float* __restrict__ wout,
                                               ushort* __restrict__ wph,
                                               ushort* __restrict__ wpl) {
    int m = blockIdx.y;
    int c = blockIdx.x * 256 + threadIdx.x;
    const float* src;
    int Nn = 128;
    size_t dstoff;
    if (m < 3)      { src = wl   + (size_t)m * 16384;       dstoff = (size_t)m * 16384; }
    else if (m < 6) { src = wr   + (size_t)(m - 3) * 16384; dstoff = (size_t)m * 16384; }
    else if (m < 8) { src = wlin + (size_t)(m - 6) * 16384; dstoff = (size_t)m * 16384; }
    else            { src = wout; Nn = 64;                  dstoff = (size_t)8 * 16384; }
    if (c >= Nn * 16) return;
    int cb = c >> 8, gg = (c >> 4) & 15, col = c & 15;
    float v[8];
#pragma unroll
    for (int j = 0; j < 8; j++)
        v[j] = src[(size_t)(gg * 8 + j) * Nn + cb * 16 + col];
    uint32x4 hv, lv;
    pack8(v, hv, lv);
    *(uint32x4*)(wph + dstoff + (size_t)c * 8) = hv;
    *(uint32x4*)(wpl + dstoff + (size_t)c * 8) = lv;
}

// ---------------- x f32 -> row-major hi/lo bf16 ----------------

__global__ __launch_bounds__(256) void k_splitx(const float* __restrict__ x,
                                                ushort* __restrict__ oh,
                                                ushort* __restrict__ ol, int N) {
    int t = blockIdx.x * 256 + threadIdx.x;
    int row = t >> 4, g = t & 15;
    if (row >= N) return;
    const float* src = x + (size_t)row * 128 + g * 8;
    float v[8];
#pragma unroll
    for (int j = 0; j < 8; j++) v[j] = src[j];
    uint32x4 hv, lv;
    pack8(v, hv, lv);
    size_t off = (size_t)row * 128 + g * 8;
    *(uint32x4*)(oh + off) = hv;
    *(uint32x4*)(ol + off) = lv;
}

// ---------------- fused layer kernel: agg + conv dual-GEMM + lin GEMM ----------------
// Block = 32 rows x 128 cols, 4 waves (each a 32-col slice), grid = ceil(N/32).
// Phase A: quarter-wave-per-node mean gather of neighbor rows (bf16-hi table)
//          -> packed hi/lo straight into LDS A-tile th/tl.
// Stage 1: conv = [act](agg@W1 + h@W2 + b1); A1 from LDS, A2 (self) from global.
//          Epilogue overwrites th/tl with the conv result (hi/lo).
// Stage 2: out = [act](conv@W3 + b2) -> global rm hi/lo, or f32 d_out (FINAL).

template <bool ACT1, int NM2, bool ACT2, bool FINAL>
__global__ __launch_bounds__(256) void k_fused(
    const ushort* __restrict__ hh,   const ushort* __restrict__ hl,
    const int* __restrict__ adj, const int* __restrict__ start,
    const int* __restrict__ deg,
    const ushort* __restrict__ w1h,  const ushort* __restrict__ w1l,
    const ushort* __restrict__ w2h,  const ushort* __restrict__ w2l,
    const float* __restrict__ b1,
    const ushort* __restrict__ w3h,  const ushort* __restrict__ w3l,
    const float* __restrict__ b2,
    ushort* __restrict__ oh, ushort* __restrict__ ol,
    float* __restrict__ of, int N) {
    constexpr int NCF2 = NM2 / 64;  // stage-2 col fragments per wave
    __shared__ ushort th[32][136];  // agg tile, then conv result (hi)
    __shared__ ushort tl[32][136];  // (lo)

    const int tid = threadIdx.x;
    const int w = tid >> 6, lane = tid & 63;
    const int g = lane >> 4, r16 = lane & 15;
    const int m0 = blockIdx.x * 32;

    // ---------------- phase A: mean aggregation into LDS ----------------
    {
        const int qw = tid >> 4;   // quarter-wave id 0..15
        const int q = tid & 15;    // lane-in-quarter: owns cols q*8..q*8+7
#pragma unroll
        for (int rep = 0; rep < 2; rep++) {
            int nr = qw + rep * 16;          // block-local row 0..31
            int node = m0 + nr;
            if (node > N - 1) node = N - 1;
            int st = start[node], cnt = deg[node];
            float a0 = 0, a1 = 0, a2 = 0, a3 = 0, a4 = 0, a5 = 0, a6 = 0, a7 = 0;
            int i = 0;
            for (; i + 4 <= cnt; i += 4) {
                int s0 = adj[st + i], s1 = adj[st + i + 1];
                int s2 = adj[st + i + 2], s3 = adj[st + i + 3];
                uint32x4 u0 = *(const uint32x4*)(hh + (size_t)s0 * 128 + q * 8);
                uint32x4 u1 = *(const uint32x4*)(hh + (size_t)s1 * 128 + q * 8);
                uint32x4 u2 = *(const uint32x4*)(hh + (size_t)s2 * 128 + q * 8);
                uint32x4 u3 = *(const uint32x4*)(hh + (size_t)s3 * 128 + q * 8);
#pragma unroll
                for (int e = 0; e < 4; e++) {
                    uint32x4 u = e == 0 ? u0 : e == 1 ? u1 : e == 2 ? u2 : u3;
                    a0 += __uint_as_float(u.x << 16); a1 += __uint_as_float(u.x & 0xffff0000u);
                    a2 += __uint_as_float(u.y << 16); a3 += __uint_as_float(u.y & 0xffff0000u);
                    a4 += __uint_as_float(u.z << 16); a5 += __uint_as_float(u.z & 0xffff0000u);
                    a6 += __uint_as_float(u.w << 16); a7 += __uint_as_float(u.w & 0xffff0000u);
                }
            }
            for (; i < cnt; i++) {
                int s0 = adj[st + i];
                uint32x4 u = *(const uint32x4*)(hh + (size_t)s0 * 128 + q * 8);
                a0 += __uint_as_float(u.x << 16); a1 += __uint_as_float(u.x & 0xffff0000u);
                a2 += __uint_as_float(u.y << 16); a3 += __uint_as_float(u.y & 0xffff0000u);
                a4 += __uint_as_float(u.z << 16); a5 += __uint_as_float(u.z & 0xffff0000u);
                a6 += __uint_as_float(u.w << 16); a7 += __uint_as_float(u.w & 0xffff0000u);
            }
            float inv = 1.0f / fmaxf((float)cnt, 1.0f);
            float v[8] = {a0 * inv, a1 * inv, a2 * inv, a3 * inv,
                          a4 * inv, a5 * inv, a6 * inv, a7 * inv};
            uint32x4 hv, lv;
            pack8(v, hv, lv);
            *(uint32x4*)&th[nr][q * 8] = hv;
            *(uint32x4*)&tl[nr][q * 8] = lv;
        }
    }
    __syncthreads();

    // ---------------- stage 1: conv dual-GEMM ----------------
    size_t ro[2];
#pragma unroll
    for (int rf = 0; rf < 2; rf++) {
        int row = m0 + rf * 16 + r16;
        if (row > N - 1) row = N - 1;
        ro[rf] = (size_t)row * 128 + g * 8;
    }

    f32x4 acc[2][2];
#pragma unroll
    for (int rf = 0; rf < 2; rf++)
#pragma unroll
        for (int cf = 0; cf < 2; cf++) acc[rf][cf] = (f32x4){0.f, 0.f, 0.f, 0.f};

#pragma unroll
    for (int s = 0; s < 4; s++) {
        bf16x8 a1h_[2], a1l_[2], a2h_[2], a2l_[2];
#pragma unroll
        for (int rf = 0; rf < 2; rf++) {
            a1h_[rf] = *(const bf16x8*)&th[rf * 16 + r16][s * 32 + g * 8];
            a1l_[rf] = *(const bf16x8*)&tl[rf * 16 + r16][s * 32 + g * 8];
            a2h_[rf] = *(const bf16x8*)(hh + ro[rf] + s * 32);
            a2l_[rf] = *(const bf16x8*)(hl + ro[rf] + s * 32);
        }
        bf16x8 b1h_[2], b1l_[2], b2h_[2], b2l_[2];
#pragma unroll
        for (int cf = 0; cf < 2; cf++) {
            size_t o = (size_t)(w * 2 + cf) * 2048 + s * 512 + g * 128 + r16 * 8;
            b1h_[cf] = *(const bf16x8*)(w1h + o);
            b1l_[cf] = *(const bf16x8*)(w1l + o);
            b2h_[cf] = *(const bf16x8*)(w2h + o);
            b2l_[cf] = *(const bf16x8*)(w2l + o);
        }
#pragma unroll
        for (int rf = 0; rf < 2; rf++)
#pragma unroll
            for (int cf = 0; cf < 2; cf++) {
                acc[rf][cf] = __builtin_amdgcn_mfma_f32_16x16x32_bf16(a1h_[rf], b1h_[cf], acc[rf][cf], 0, 0, 0);
                acc[rf][cf] = __builtin_amdgcn_mfma_f32_16x16x32_bf16(a1h_[rf], b1l_[cf], acc[rf][cf], 0, 0, 0);
                acc[rf][cf] = __builtin_amdgcn_mfma_f32_16x16x32_bf16(a1l_[rf], b1h_[cf], acc[rf][cf], 0, 0, 0);
                acc[rf][cf] = __builtin_amdgcn_mfma_f32_16x16x32_bf16(a2h_[rf], b2h_[cf], acc[rf][cf], 0, 0, 0);
                acc[rf][cf] = __builtin_amdgcn_mfma_f32_16x16x32_bf16(a2h_[rf], b2l_[cf], acc[rf][cf], 0, 0, 0);
                acc[rf][cf] = __builtin_amdgcn_mfma_f32_16x16x32_bf16(a2l_[rf], b2h_[cf], acc[rf][cf], 0, 0, 0);
            }
    }
    __syncthreads();  // all stage-1 LDS reads done before overwrite

    // ---------------- epilogue 1: bias/act -> conv hi/lo into th/tl ----------------
    {
        float bv1[2];
#pragma unroll
        for (int cf = 0; cf < 2; cf++) bv1[cf] = b1[(w * 2 + cf) * 16 + r16];
#pragma unroll
        for (int rf = 0; rf < 2; rf++)
#pragma unroll
            for (int cf = 0; cf < 2; cf++)
#pragma unroll
                for (int i = 0; i < 4; i++) {
                    float v = acc[rf][cf][i] + bv1[cf];
                    if (ACT1) v = v > 0.f ? v : NEG_SLOPE * v;
                    ushort hi = f2bf(v);
                    ushort lo = f2bf(v - bf2f(hi));
                    th[rf * 16 + g * 4 + i][w * 32 + cf * 16 + r16] = hi;
                    tl[rf * 16 + g * 4 + i][w * 32 + cf * 16 + r16] = lo;
                }
    }
    __syncthreads();

    // ---------------- stage 2: out GEMM (A from LDS th/tl) ----------------
    f32x4 acc2[2][NCF2];
#pragma unroll
    for (int rf = 0; rf < 2; rf++)
#pragma unroll
        for (int cf = 0; cf < NCF2; cf++) acc2[rf][cf] = (f32x4){0.f, 0.f, 0.f, 0.f};

#pragma unroll
    for (int s = 0; s < 4; s++) {
        bf16x8 ah_[2], al_[2];
#pragma unroll
        for (int rf = 0; rf < 2; rf++) {
            ah_[rf] = *(const bf16x8*)&th[rf * 16 + r16][s * 32 + g * 8];
            al_[rf] = *(const bf16x8*)&tl[rf * 16 + r16][s * 32 + g * 8];
        }
        bf16x8 wh_[NCF2], wlo_[NCF2];
#pragma unroll
        for (int cf = 0; cf < NCF2; cf++) {
            size_t o = (size_t)(w * NCF2 + cf) * 2048 + s * 512 + g * 128 + r16 * 8;
            wh_[cf] = *(const bf16x8*)(w3h + o);
            wlo_[cf] = *(const bf16x8*)(w3l + o);
        }
#pragma unroll
        for (int rf = 0; rf < 2; rf++)
#pragma unroll
            for (int cf = 0; cf < NCF2; cf++) {
                acc2[rf][cf] = __builtin_amdgcn_mfma_f32_16x16x32_bf16(ah_[rf], wh_[cf], acc2[rf][cf], 0, 0, 0);
                acc2[rf][cf] = __builtin_amdgcn_mfma_f32_16x16x32_bf16(ah_[rf], wlo_[cf], acc2[rf][cf], 0, 0, 0);
                acc2[rf][cf] = __builtin_amdgcn_mfma_f32_16x16x32_bf16(al_[rf], wh_[cf], acc2[rf][cf], 0, 0, 0);
            }
    }

    // ---------------- epilogue 2 ----------------
    if constexpr (FINAL) {
        float bv2 = b2[w * 16 + r16];
#pragma unroll
        for (int rf = 0; rf < 2; rf++)
#pragma unroll
            for (int i = 0; i < 4; i++) {
                int row = m0 + rf * 16 + g * 4 + i;
                if (row < N) of[(size_t)row * 64 + w * 16 + r16] = acc2[rf][0][i] + bv2;
            }
    } else {
        __syncthreads();  // all stage-2 reads of th/tl done before reuse
        float bv2[2];
#pragma unroll
        for (int cf = 0; cf < 2; cf++) bv2[cf] = b2[(w * 2 + cf) * 16 + r16];
#pragma unroll
        for (int rf = 0; rf < 2; rf++)
#pragma unroll
            for (int cf = 0; cf < 2; cf++)
#pragma unroll
                for (int i = 0; i < 4; i++) {
                    float v = acc2[rf][cf][i] + bv2[cf];
                    if (ACT2) v = v > 0.f ? v : NEG_SLOPE * v;
                    ushort hi = f2bf(v);
                    ushort lo = f2bf(v - bf2f(hi));
                    th[rf * 16 + g * 4 + i][w * 32 + cf * 16 + r16] = hi;
                    tl[rf * 16 + g * 4 + i][w * 32 + cf * 16 + r16] = lo;
                }
        __syncthreads();
#pragma unroll
        for (int rep = 0; rep < 2; rep++) {
            int id = rep * 256 + tid;       // 0..511
            int row = id >> 4, kg = id & 15;
            int grow = m0 + row;
            if (grow < N) {
                uint32x4 hv = *(const uint32x4*)&th[row][kg * 8];
                uint32x4 lv = *(const uint32x4*)&tl[row][kg * 8];
                *(uint32x4*)(oh + (size_t)grow * 128 + kg * 8) = hv;
                *(uint32x4*)(ol + (size_t)grow * 128 + kg * 8) = lv;
            }
        }
    }
}

// ---------------- launch ----------------

extern "C" void kernel_launch(void* const* d_in, const int* in_sizes, int n_in,
                              void* d_out, int out_size, void* d_ws, size_t ws_size,
                              hipStream_t stream) {
    const float* x    = (const float*)d_in[0];
    const int*   ei   = (const int*)d_in[1];
    const float* wl   = (const float*)d_in[2];
    const float* wr   = (const float*)d_in[3];
    const float* bc   = (const float*)d_in[4];
    const float* wlin = (const float*)d_in[5];
    const float* blin = (const float*)d_in[6];
    const float* wout = (const float*)d_in[7];
    const float* bout = (const float*)d_in[8];
    float* out = (float*)d_out;

    const int N = in_sizes[0] / 128;
    const int E = in_sizes[1] / 2;

    char* p = (char*)d_ws;
    auto alloc = [&](size_t bytes) {
        char* r = p;
        p += (bytes + 255) & ~(size_t)255;
        return r;
    };
    int* counter = (int*)alloc(4);
    int* degp    = (int*)alloc((size_t)N * 16 * 4);  // padded: 1 counter / 64B line
    int* deg     = (int*)alloc((size_t)N * 4);
    int* start   = (int*)alloc((size_t)N * 4);
    int* rank    = (int*)alloc((size_t)E * 4);
    int* adj     = (int*)alloc((size_t)E * 4);
    ushort* wph  = (ushort*)alloc((size_t)139264 * 2);
    ushort* wpl  = (ushort*)alloc((size_t)139264 * 2);
    ushort* xh   = (ushort*)alloc((size_t)N * 128 * 2);  // reused as layer-1 output
    ushort* xl   = (ushort*)alloc((size_t)N * 128 * 2);
    ushort* hAh  = (ushort*)alloc((size_t)N * 128 * 2);  // layer-0 output
    ushort* hAl  = (ushort*)alloc((size_t)N * 128 * 2);

    // zero counter + degp (contiguous at the front of ws)
    hipMemsetAsync(d_ws, 0, (size_t)((char*)(degp + (size_t)N * 16) - (char*)d_ws), stream);

    const int gE = (E + 255) / 256;
    const int gN = (N + 255) / 256;
    const int gQ = (N * 16 + 255) / 256;
    const int gF = (N + 31) / 32;   // fused layer blocks (32 rows)

    k_count <<<gE, 256, 0, stream>>>(ei, E, degp, rank);
    k_starts<<<gN, 256, 0, stream>>>(degp, N, start, deg, counter);
    k_fill  <<<gE, 256, 0, stream>>>(ei, E, start, rank, adj);
    k_wpack <<<dim3(8, 9), 256, 0, stream>>>(wl, wr, wlin, wout, wph, wpl);
    k_splitx<<<gQ, 256, 0, stream>>>(x, xh, xl, N);

    const ushort *wl0h = wph,           *wl0l = wpl;
    const ushort *wl1h = wph + 16384,   *wl1l = wpl + 16384;
    const ushort *wl2h = wph + 32768,   *wl2l = wpl + 32768;
    const ushort *wr0h = wph + 3*16384, *wr0l = wpl + 3*16384;
    const ushort *wr1h = wph + 4*16384, *wr1l = wpl + 4*16384;
    const ushort *wr2h = wph + 5*16384, *wr2l = wpl + 5*16384;
    const ushort *wn0h = wph + 6*16384, *wn0l = wpl + 6*16384;
    const ushort *wn1h = wph + 7*16384, *wn1l = wpl + 7*16384;
    const ushort *woh  = wph + 8*16384, *wol  = wpl + 8*16384;

    // layer 0: h = x
    k_fused<true, 128, true, false><<<gF, 256, 0, stream>>>(
        xh, xl, adj, start, deg, wl0h, wl0l, wr0h, wr0l, bc,
        wn0h, wn0l, blin, hAh, hAl, nullptr, N);
    // layer 1: h = hA -> writes xh/xl (x dead)
    k_fused<true, 128, true, false><<<gF, 256, 0, stream>>>(
        hAh, hAl, adj, start, deg, wl1h, wl1l, wr1h, wr1l, bc + 128,
        wn1h, wn1l, blin + 128, xh, xl, nullptr, N);
    // layer 2: conv (no act) + wout projection -> d_out
    k_fused<false, 64, false, true><<<gF, 256, 0, stream>>>(
        xh, xl, adj, start, deg, wl2h, wl2l, wr2h, wr2l, bc + 256,
        woh, wol, bout, nullptr, nullptr, out, N);
}